// Round 16
// baseline (399.300 us; speedup 1.0000x reference)
//
#include <hip/hip_runtime.h>
#include <hip/hip_bf16.h>
#include <math.h>

#define NN   32768
#define BG   32
#define NPG  1024
#define HD   64
#define KK   24          // neighbors

#define FLTMAX 3.402823466e38f

typedef __attribute__((ext_vector_type(8))) short short8;
typedef __attribute__((ext_vector_type(4))) float f32x4;

__device__ __forceinline__ float elu1(float x) { return x > 0.f ? x : expm1f(x); }

__device__ __forceinline__ unsigned short f2bf(float x) {  // RNE to bf16
  unsigned u = __float_as_uint(x);
  unsigned r = (u + 0x7FFFu + ((u >> 16) & 1u)) >> 16;
  return (unsigned short)r;
}
__device__ __forceinline__ float bf2f(unsigned short h) {
  return __uint_as_float(((unsigned)h) << 16);
}
// monotone float -> uint order transform (finite values)
__device__ __forceinline__ unsigned ordf(float f) {
  unsigned b = __float_as_uint(f);
  return (b & 0x80000000u) ? ~b : (b | 0x80000000u);
}

// async global->LDS, 16B per lane; lds base must be wave-uniform (HW adds lane*16)
__device__ __forceinline__ void gl_lds16(const void* g, void* lds) {
  __builtin_amdgcn_global_load_lds(
      (const __attribute__((address_space(1))) unsigned int*)g,
      (__attribute__((address_space(3))) unsigned int*)lds, 16, 0, 0);
}

// ---------------- input MLP (+ folded-in Wc fragment conversion blocks) ----------------
__global__ void __launch_bounds__(256) k_mlp_in(
    const float* __restrict__ x, const float* __restrict__ W1, const float* __restrict__ b1,
    const float* __restrict__ W2, const float* __restrict__ b2, float* __restrict__ F,
    const float* __restrict__ Wc0, const float* __restrict__ Wc1,
    const float* __restrict__ Wc2, unsigned char* __restrict__ Wf) {
  __shared__ float sW1[8*64];
  __shared__ float sW2[64*64];
  __shared__ float sb1[64];
  __shared__ float sb2[64];
  int t = threadIdx.x;
  if (blockIdx.x >= NN/128) {
    int lb = blockIdx.x - NN/128;
    const float* Wc = lb == 0 ? Wc0 : (lb == 1 ? Wc1 : Wc2);
    unsigned char* dst = Wf + (size_t)lb*32768;
    int f = t >> 1, colHalf = t & 1;
    int part = f & 1, nt = (f >> 1) & 7, oct = (f >> 4) & 3, ks = f >> 6;
#pragma unroll
    for (int cc = 0; cc < 8; ++cc) {
      int c8 = colHalf*8 + cc;
      int dp = nt*16 + c8;
      const float* wsrc = (dp < 64) ? (Wc + dp) : (Wc + 64*64 + (dp - 64));
      unsigned short sh[8];
#pragma unroll
      for (int j = 0; j < 8; ++j) {
        float w = wsrc[(ks*32 + oct*8 + j)*64];
        unsigned short hi = f2bf(w);
        sh[j] = part ? f2bf(w - bf2f(hi)) : hi;
      }
      *reinterpret_cast<int4*>(dst + f*256 + c8*16) = make_int4(
          (unsigned)sh[0] | ((unsigned)sh[1] << 16), (unsigned)sh[2] | ((unsigned)sh[3] << 16),
          (unsigned)sh[4] | ((unsigned)sh[5] << 16), (unsigned)sh[6] | ((unsigned)sh[7] << 16));
    }
    return;
  }
  for (int i = t; i < 8*64; i += 256) sW1[i] = W1[i];
  for (int i = t; i < 64*64; i += 256) sW2[i] = W2[i];
  if (t < 64) { sb1[t] = b1[t]; sb2[t] = b2[t]; }
  __syncthreads();
  int node = blockIdx.x*128 + (t & 127);
  int half = t >> 7;
  float xr[8];
#pragma unroll
  for (int i = 0; i < 8; ++i) xr[i] = x[node*8 + i];
  float h1[64];
#pragma unroll 8
  for (int k = 0; k < 64; ++k) {
    float a = sb1[k];
#pragma unroll
    for (int i = 0; i < 8; ++i) a += xr[i]*sW1[i*64+k];
    h1[k] = elu1(a);
  }
#pragma unroll 2
  for (int dd = 0; dd < 32; ++dd) {
    int d = half*32 + dd;
    float a = sb2[d];
#pragma unroll
    for (int k = 0; k < 64; ++k) a += h1[k]*sW2[k*64+d];
    F[node*64 + d] = elu1(a);
  }
}

// split-bf16 conv-buffer addressing
__device__ __forceinline__ int conv_off(int node, int g) {
  return node*256 + ((((g & 7) ^ (node & 7)) | (g & 8)) << 4);
}

// ---- per-layer (MFMA): U = X@(A-B)+bc, V = X@B (fp32), SQ, XB = split-bf16(X) ----
// (UNCHANGED from r13/r14/r15 — passed at absmax 0.265625.)
__global__ void __launch_bounds__(256) k_uv(
    const float* __restrict__ X, const unsigned char* __restrict__ Wf,
    const float* __restrict__ bc,
    float* __restrict__ U, float* __restrict__ V, float* __restrict__ SQ,
    unsigned char* __restrict__ XB) {
  __shared__ __align__(16) unsigned char sConv[64*256];
  __shared__ __align__(16) unsigned char sWf[128*256];
  __shared__ float sbc[64];
  int t = threadIdx.x;
  const int lane = t & 63, wave = t >> 6;
  const int g4 = lane >> 4, a15 = lane & 15;
  int b = blockIdx.x;
  int graph = (b & 7) + 8*(b >> 7);
  int nig0 = ((b >> 3) & 15) * 64;
  int base = graph*1024 + nig0;

  if (t < 64) sbc[t] = bc[t];

#pragma unroll
  for (int i = 0; i < 8; ++i) {
    int I = wave*8 + i;
    gl_lds16(Wf + (size_t)I*1024 + lane*16, (void*)(sWf + I*1024));
  }

  {
    int ln = t >> 2, q2 = t & 3;
    int ks = q2 >> 1, oh = (q2 & 1) * 2;
    const float* src = X + (size_t)(base + ln)*64 + ks*32 + oh*8;
    unsigned hu[8], lu[8];
    float sq = 0.f;
#pragma unroll
    for (int q = 0; q < 4; ++q) {
      float4 f = *reinterpret_cast<const float4*>(src + q*4);
      sq += f.x*f.x + f.y*f.y + f.z*f.z + f.w*f.w;
      unsigned short h0 = f2bf(f.x), h1 = f2bf(f.y), h2 = f2bf(f.z), h3 = f2bf(f.w);
      unsigned short l0 = f2bf(f.x - bf2f(h0)), l1 = f2bf(f.y - bf2f(h1));
      unsigned short l2 = f2bf(f.z - bf2f(h2)), l3 = f2bf(f.w - bf2f(h3));
      hu[q*2]   = (unsigned)h0 | ((unsigned)h1 << 16);
      hu[q*2+1] = (unsigned)h2 | ((unsigned)h3 << 16);
      lu[q*2]   = (unsigned)l0 | ((unsigned)l1 << 16);
      lu[q*2+1] = (unsigned)l2 | ((unsigned)l3 << 16);
    }
    sq += __shfl_xor(sq, 1);
    sq += __shfl_xor(sq, 2);
    if (q2 == 0) SQ[base + ln] = sq;
    unsigned char* gdst = XB + (((size_t)graph*2 + ks)*1024 + nig0 + ln)*128 + oh*16;
#pragma unroll
    for (int o = 0; o < 2; ++o) {
      int4 hp = make_int4(hu[o*4], hu[o*4+1], hu[o*4+2], hu[o*4+3]);
      int4 lp = make_int4(lu[o*4], lu[o*4+1], lu[o*4+2], lu[o*4+3]);
      *reinterpret_cast<int4*>(sConv + conv_off(ln, ks*8 + oh + o))     = hp;
      *reinterpret_cast<int4*>(sConv + conv_off(ln, ks*8 + 4 + oh + o)) = lp;
      *reinterpret_cast<int4*>(gdst + o*16)      = hp;
      *reinterpret_cast<int4*>(gdst + 64 + o*16) = lp;
    }
  }
  __syncthreads();

  f32x4 acc[8];
#pragma unroll
  for (int n = 0; n < 8; ++n) acc[n] = f32x4{0.f, 0.f, 0.f, 0.f};
#pragma unroll
  for (int ks = 0; ks < 2; ++ks) {
    int node = wave*16 + a15;
    short8 ah = *reinterpret_cast<const short8*>(sConv + conv_off(node, ks*8 + g4));
    short8 al = *reinterpret_cast<const short8*>(sConv + conv_off(node, ks*8 + 4 + g4));
#pragma unroll
    for (int nt = 0; nt < 8; ++nt) {
      int fb = ((ks*4 + g4)*8 + nt)*2;
      short8 bh = *reinterpret_cast<const short8*>(sWf + fb*256 + a15*16);
      short8 bl = *reinterpret_cast<const short8*>(sWf + (fb+1)*256 + a15*16);
      acc[nt] = __builtin_amdgcn_mfma_f32_16x16x32_bf16(ah, bh, acc[nt], 0, 0, 0);
      acc[nt] = __builtin_amdgcn_mfma_f32_16x16x32_bf16(ah, bl, acc[nt], 0, 0, 0);
      acc[nt] = __builtin_amdgcn_mfma_f32_16x16x32_bf16(al, bh, acc[nt], 0, 0, 0);
      acc[nt] = __builtin_amdgcn_mfma_f32_16x16x32_bf16(al, bl, acc[nt], 0, 0, 0);
    }
  }

#pragma unroll
  for (int nt = 0; nt < 4; ++nt) {
    float bcv = sbc[nt*16 + a15];
#pragma unroll
    for (int i = 0; i < 4; ++i) {
      size_t row = base + wave*16 + g4*4 + i;
      float p = acc[nt][i], q = acc[nt+4][i];
      U[row*64 + nt*16 + a15] = p - q + bcv;
      V[row*64 + nt*16 + a15] = q;
    }
  }
}

// read-side LDS addressing for staged columns
__device__ __forceinline__ int col_byte(int node, int granule) {
  return node*128 + ((granule ^ (node & 7)) << 4);
}

// ------- knn + fused aggregate. 1024 thr / 16 waves / 64 rows per block.
// MODE 0: plain (aggregate -> F).  MODE 1: last (fused output MLP, r15-verified).
// MODE 2: fused next-layer k_uv tail (writes Un/Vn/SQn/XBn from new F rows).
template<int MODE>
__global__ void __launch_bounds__(1024, 8) k_knn(
    const unsigned char* __restrict__ XB, const float* __restrict__ SQ,
    const float* __restrict__ U, const float* __restrict__ V,
    float* __restrict__ F,
    const float* __restrict__ Wo1, const float* __restrict__ bo1,
    const float* __restrict__ Wo2, const float* __restrict__ bo2,
    const float* __restrict__ Wo3, const float* __restrict__ bo3,
    const int* __restrict__ batch, float* __restrict__ out, int out_size,
    const unsigned char* __restrict__ WfN, const float* __restrict__ bcN,
    float* __restrict__ Un, float* __restrict__ Vn, float* __restrict__ SQn,
    unsigned char* __restrict__ XBn) {
  __shared__ __align__(16) unsigned char sBuf[49152];    // dbuf -> dist -> sCmp -> tail bufs
  __shared__ __align__(16) unsigned char sRowB[64*272];  // rows -> (tail) new-F rows
  __shared__ float sCsq[1024];
  __shared__ int nIdx[64*KK];

  int b = blockIdx.x;
  int g = (b & 7) + 8*(b >> 7);          // graph -> XCD g%8 (512 blocks)
  int rowBase = ((b >> 3) & 15) * 64;
  int gbase = g * NPG;
  int t = threadIdx.x;
  const int lane = t & 63, w = t >> 6;
  const int g4 = lane >> 4, a15 = lane & 15;
  const int rg = w >> 2, wc = w & 3;

  // ---- stage 64 row fragments + column squared norms ----
  {
    int row = t >> 4, part = t & 15;
    int ks = part >> 3, o = part & 7;
    const unsigned char* src =
        XB + (((size_t)g*2 + ks)*1024 + rowBase + row)*128 + o*16;
    *reinterpret_cast<int4*>(sRowB + row*272 + part*16) =
        *reinterpret_cast<const int4*>(src);
    if (t < 256) {
      float4 q = *reinterpret_cast<const float4*>(SQ + gbase + t*4);
      *reinterpret_cast<float4*>(sCsq + t*4) = q;
    }
  }
  // prologue: stage chunks 0,1 into bufs 0,1
  {
    int n = t >> 3, gq = t & 7;
    int srcChunk = (n << 3) + (gq ^ (n & 7));
    const unsigned char* sl0 = XB + (((size_t)g*2 + 0)*1024)*128;
    gl_lds16(sl0 + (size_t)srcChunk*16, (void*)(sBuf + 0*16384 + w*1024));
    const unsigned char* sl1 = XB + (((size_t)g*2 + 1)*1024)*128;
    gl_lds16(sl1 + (size_t)srcChunk*16, (void*)(sBuf + 1*16384 + w*1024));
  }
  __syncthreads();

  short8 ahf[2], alf[2];
#pragma unroll
  for (int ks = 0; ks < 2; ++ks) {
    ahf[ks] = *reinterpret_cast<const short8*>(
        sRowB + (rg*16 + a15)*272 + ks*128 + (g4 << 4));
    alf[ks] = *reinterpret_cast<const short8*>(
        sRowB + (rg*16 + a15)*272 + ks*128 + 64 + (g4 << 4));
  }

  f32x4 acc[16];
#pragma unroll
  for (int i = 0; i < 16; ++i) acc[i] = f32x4{0.f, 0.f, 0.f, 0.f};

  // ---- Gram over 16 chunks, 2-deep prefetch, counted vmcnt ----
#pragma unroll
  for (int c = 0; c < 16; ++c) {
    if (c) {
      if (c < 15) asm volatile("s_waitcnt vmcnt(1)" ::: "memory");
      else        asm volatile("s_waitcnt vmcnt(0)" ::: "memory");
      __builtin_amdgcn_sched_barrier(0);
      __builtin_amdgcn_s_barrier();
    }
    if (c < 14) {
      int cn = c + 2;
      const unsigned char* sl =
          XB + (((size_t)g*2 + (cn & 1))*1024 + (cn >> 1)*128)*128;
      int n = t >> 3, gq = t & 7;
      int srcChunk = (n << 3) + (gq ^ (n & 7));
      gl_lds16(sl + (size_t)srcChunk*16, (void*)(sBuf + (cn % 3)*16384 + w*1024));
    }
    const unsigned char* bufc = sBuf + (c % 3)*16384;
    short8 ah = ahf[c & 1], al = alf[c & 1];
#pragma unroll
    for (int tt = 0; tt < 2; ++tt) {
      int node = wc*32 + tt*16 + a15;
      short8 bh = *reinterpret_cast<const short8*>(bufc + col_byte(node, g4));
      short8 bl = *reinterpret_cast<const short8*>(bufc + col_byte(node, 4 + g4));
      int ai = (c >> 1)*2 + tt;
      acc[ai] = __builtin_amdgcn_mfma_f32_16x16x32_bf16(ah, bh, acc[ai], 0, 0, 0);
      acc[ai] = __builtin_amdgcn_mfma_f32_16x16x32_bf16(ah, bl, acc[ai], 0, 0, 0);
      acc[ai] = __builtin_amdgcn_mfma_f32_16x16x32_bf16(al, bh, acc[ai], 0, 0, 0);
      acc[ai] = __builtin_amdgcn_mfma_f32_16x16x32_bf16(al, bl, acc[ai], 0, 0, 0);
    }
  }

  // ---- transpose acc -> per-wave selection regs (r12 geometry) ----
  float v[4][16];
  float* dL = (float*)sBuf;
#pragma unroll
  for (int e = 0; e < 8; ++e) {
    __syncthreads();
#pragma unroll
    for (int k2 = 0; k2 < 2; ++k2) {
      int ai = e*2 + k2;
      int lc = wc*32 + k2*16 + a15;
      float cs = sCsq[e*128 + lc];
#pragma unroll
      for (int i = 0; i < 4; ++i) {
        int r64 = rg*16 + g4*4 + i;
        dL[r64*128 + (lc ^ (((r64 >> 2) & 3) << 3))] = cs - 2.0f*acc[ai][i];
      }
    }
    __syncthreads();
#pragma unroll
    for (int m2 = 0; m2 < 2; ++m2)
#pragma unroll
      for (int r = 0; r < 4; ++r) {
        int rr = w*4 + r;
        v[r][e*2 + m2] = dL[rr*128 + ((m2*64 + lane) ^ (((rr >> 2) & 3) << 3))];
      }
  }
  __syncthreads();

  unsigned long long* sCmp = (unsigned long long*)sBuf;
  const unsigned long long mlt = (1ull << lane) - 1ull;

  unsigned uu[4];
#pragma unroll
  for (int r = 0; r < 4; ++r) {
    float bm = v[r][0];
#pragma unroll
    for (int m = 1; m < 16; ++m) bm = fminf(bm, v[r][m]);
    uu[r] = ordf(bm);
  }

  unsigned pp[4] = {0u, 0u, 0u, 0u};
#pragma unroll
  for (int bb = 31; bb >= 0; --bb) {
#pragma unroll
    for (int r = 0; r < 4; ++r) {
      unsigned q = pp[r] | (1u << bb);
      if ((int)__popcll(__ballot(uu[r] < q)) < KK) pp[r] = q;
    }
  }

  int total[4];
#pragma unroll
  for (int r = 0; r < 4; ++r) {
    int base = 0;
#pragma unroll
    for (int m = 0; m < 16; ++m) {
      unsigned ov = ordf(v[r][m]);
      bool f = ov <= pp[r];
      unsigned long long bal = __ballot(f);
      int slot = base + (int)__popcll(bal & mlt);
      if (f && slot < 64)
        sCmp[(w*4 + r)*64 + slot] =
            ((unsigned long long)ov << 32) | (unsigned)(lane + (m << 6));
      base += (int)__popcll(bal);
    }
    total[r] = base;
  }

  unsigned cu2[4]; int col2[4];
#pragma unroll
  for (int r = 0; r < 4; ++r) {
    unsigned long long kp = (lane < total[r]) ? sCmp[(w*4 + r)*64 + lane] : ~0ull;
    cu2[r] = (unsigned)(kp >> 32);
    col2[r] = (int)(unsigned)(kp & 0xFFFFFFFFull);
  }

  if (MODE == 2) {
    // sCmp consumed; stage next-layer W fragments (32 KB) into sBuf[0..32768)
    __syncthreads();
#pragma unroll
    for (int i = 0; i < 2; ++i) {
      int I = w*2 + i;
      gl_lds16(WfN + (size_t)I*1024 + lane*16, (void*)(sBuf + I*1024));
    }
  }

  unsigned p2[4] = {0u, 0u, 0u, 0u};
#pragma unroll
  for (int bb = 31; bb >= 0; --bb) {
#pragma unroll
    for (int r = 0; r < 4; ++r) {
      unsigned q = p2[r] | (1u << bb);
      if ((int)__popcll(__ballot(cu2[r] < q)) < KK) p2[r] = q;
    }
  }
  int need[4]; bool tie[4];
#pragma unroll
  for (int r = 0; r < 4; ++r) {
    need[r] = KK - (int)__popcll(__ballot(cu2[r] < p2[r]));
    tie[r] = (cu2[r] == p2[r]);
  }
  unsigned p3[4] = {0u, 0u, 0u, 0u};
#pragma unroll
  for (int bb = 9; bb >= 0; --bb) {
#pragma unroll
    for (int r = 0; r < 4; ++r) {
      unsigned q = p3[r] | (1u << bb);
      if ((int)__popcll(__ballot(tie[r] && ((unsigned)col2[r] < q))) < need[r]) p3[r] = q;
    }
  }

  bool allfast = total[0] <= 64 && total[1] <= 64 && total[2] <= 64 && total[3] <= 64;
  if (allfast) {
#pragma unroll
    for (int r = 0; r < 4; ++r) {
      bool in24 = (cu2[r] < p2[r]) || (tie[r] && ((unsigned)col2[r] <= p3[r]));
      unsigned long long ball = __ballot(in24);
      int pos = (int)__popcll(ball & mlt);
      if (in24) nIdx[(w*4 + r)*KK + pos] = col2[r];
    }
  } else {
#pragma unroll
    for (int r = 0; r < 4; ++r) {
      unsigned selm = 0;
      for (int it = 0; it < KK; ++it) {
        float bv = FLTMAX; int bj = 0x7fffffff;
#pragma unroll
        for (int m = 0; m < 16; ++m) {
          float vv = ((selm >> m) & 1) ? FLTMAX : v[r][m];
          int col = lane + (m << 6);
          bool bsel = vv < bv; bv = bsel ? vv : bv; bj = bsel ? col : bj;
        }
#pragma unroll
        for (int s = 32; s; s >>= 1) {
          float ov = __shfl_xor(bv, s); int oj = __shfl_xor(bj, s);
          bool bsel = (ov < bv) || (ov == bv && oj < bj);
          bv = bsel ? ov : bv; bj = bsel ? oj : bj;
        }
        if (lane == (bj & 63)) selm |= 1u << (bj >> 6);
        if (lane == 0) nIdx[(w*4 + r)*KK + it] = bj;
      }
    }
  }

  // ---- fused aggregate ----
  if (MODE == 0) {
#pragma unroll
    for (int r = 0; r < 4; ++r) {
      int row = rowBase + w*4 + r;
      float mx = -FLTMAX;
#pragma unroll
      for (int tt = 0; tt < KK; ++tt) {
        int j = nIdx[(w*4 + r)*KK + tt];
        mx = fmaxf(mx, V[((size_t)(gbase + j))*64 + lane]);
      }
      size_t off = (size_t)(gbase + row)*64 + lane;
      F[off] += elu1(U[off] + mx);
    }
  } else if (MODE == 1) {
    // rows -> LDS, then fused output MLP (r15-verified, bit-identical to k_out)
    float* sOutF = (float*)sRowB;              // [64][68]
#pragma unroll
    for (int r = 0; r < 4; ++r) {
      int row = rowBase + w*4 + r;
      float mx = -FLTMAX;
#pragma unroll
      for (int tt = 0; tt < KK; ++tt) {
        int j = nIdx[(w*4 + r)*KK + tt];
        mx = fmaxf(mx, V[((size_t)(gbase + j))*64 + lane]);
      }
      size_t off = (size_t)(gbase + row)*64 + lane;
      sOutF[(w*4 + r)*68 + lane] = F[off] + elu1(U[off] + mx);
    }
    __syncthreads();

    float* sW1o = (float*)sBuf;
    float* sW2o = sW1o + 64*64;
    float* sW3o = sW2o + 64*32;
    float* sB1o = sW3o + 32*8;
    float* sB2o = sB1o + 64;
    float* sB3o = sB2o + 32;
    float* sO1  = sB3o + 8;
    for (int i = t; i < 64*64; i += 1024) sW1o[i] = Wo1[i];
    for (int i = t; i < 64*32; i += 1024) sW2o[i] = Wo2[i];
    if (t < 256) sW3o[t] = Wo3[t];
    if (t < 64) sB1o[t] = bo1[t];
    if (t < 32) sB2o[t] = bo2[t];
    if (t < 8)  sB3o[t] = bo3[t];
    __syncthreads();

    int ln = t >> 3, qd = t & 7;
    if (t < 512) {
      float a1[8];
#pragma unroll
      for (int dd = 0; dd < 8; ++dd) a1[dd] = sB1o[qd*8 + dd];
#pragma unroll 4
      for (int k = 0; k < 64; ++k) {
        float fk = sOutF[ln*68 + k];
#pragma unroll
        for (int dd = 0; dd < 8; ++dd) a1[dd] += fk*sW1o[k*64 + qd*8 + dd];
      }
#pragma unroll
      for (int dd = 0; dd < 8; ++dd) sO1[ln*65 + qd*8 + dd] = elu1(a1[dd]);
    }
    __syncthreads();

    float* sO2 = (float*)sRowB;
    if (t < 512) {
      float a2[4];
#pragma unroll
      for (int dd = 0; dd < 4; ++dd) a2[dd] = sB2o[qd*4 + dd];
#pragma unroll 4
      for (int k = 0; k < 64; ++k) {
        float ok = sO1[ln*65 + k];
#pragma unroll
        for (int dd = 0; dd < 4; ++dd) a2[dd] += ok*sW2o[k*32 + qd*4 + dd];
      }
#pragma unroll
      for (int dd = 0; dd < 4; ++dd) sO2[ln*34 + qd*4 + dd] = elu1(a2[dd]);
    }
    __syncthreads();

    if (t < 512) {
      int nodeG = gbase + rowBase + ln;
      float a3 = sB3o[qd];
#pragma unroll
      for (int k = 0; k < 32; ++k) a3 += sO2[ln*34 + k]*sW3o[k*8 + qd];
      out[(size_t)nodeG*8 + qd] = a3;
      if (qd == 0 && out_size >= NN*9) out[(size_t)NN*8 + nodeG] = (float)batch[nodeG];
    }
  } else {
    // MODE 2: aggregate -> F global + LDS, then fused next-layer k_uv tail
    float* sOutF = (float*)sRowB;              // [64][68]
#pragma unroll
    for (int r = 0; r < 4; ++r) {
      int row = rowBase + w*4 + r;
      float mx = -FLTMAX;
#pragma unroll
      for (int tt = 0; tt < KK; ++tt) {
        int j = nIdx[(w*4 + r)*KK + tt];
        mx = fmaxf(mx, V[((size_t)(gbase + j))*64 + lane]);
      }
      size_t off = (size_t)(gbase + row)*64 + lane;
      float nf = F[off] + elu1(U[off] + mx);
      F[off] = nf;
      sOutF[(w*4 + r)*68 + lane] = nf;
    }
    asm volatile("s_waitcnt vmcnt(0)" ::: "memory");   // WfN staging done
    __builtin_amdgcn_sched_barrier(0);
    __syncthreads();                                    // sOutF complete block-wide

    // conversion: EXACT k_uv phase-A code on threads t<256 (same mapping ->
    // bit-identical SQ/XB), source = sOutF LDS, sConv target = sBuf[32K..48K)
    unsigned char* sConvT = sBuf + 32768;
    if (t < 256) {
      int ln = t >> 2, q2 = t & 3;
      int ks = q2 >> 1, oh = (q2 & 1) * 2;
      const float* src = sOutF + ln*68 + ks*32 + oh*8;
      unsigned hu[8], lu[8];
      float sq = 0.f;
#pragma unroll
      for (int q = 0; q < 4; ++q) {
        float4 f = *reinterpret_cast<const float4*>(src + q*4);
        sq += f.x*f.x + f.y*f.y + f.z*f.z + f.w*f.w;
        unsigned short h0 = f2bf(f.x), h1 = f2bf(f.y), h2 = f2bf(f.z), h3 = f2bf(f.w);
        unsigned short l0 = f2bf(f.x - bf2f(h0)), l1 = f2bf(f.y - bf2f(h1));
        unsigned short l2 = f2bf(f.z - bf2f(h2)), l3 = f2bf(f.w - bf2f(h3));
        hu[q*2]   = (unsigned)h0 | ((unsigned)h1 << 16);
        hu[q*2+1] = (unsigned)h2 | ((unsigned)h3 << 16);
        lu[q*2]   = (unsigned)l0 | ((unsigned)l1 << 16);
        lu[q*2+1] = (unsigned)l2 | ((unsigned)l3 << 16);
      }
      sq += __shfl_xor(sq, 1);
      sq += __shfl_xor(sq, 2);
      if (q2 == 0) SQn[gbase + rowBase + ln] = sq;
      unsigned char* gdst = XBn + (((size_t)g*2 + ks)*1024 + rowBase + ln)*128 + oh*16;
#pragma unroll
      for (int o = 0; o < 2; ++o) {
        int4 hp = make_int4(hu[o*4], hu[o*4+1], hu[o*4+2], hu[o*4+3]);
        int4 lp = make_int4(lu[o*4], lu[o*4+1], lu[o*4+2], lu[o*4+3]);
        *reinterpret_cast<int4*>(sConvT + conv_off(ln, ks*8 + oh + o))     = hp;
        *reinterpret_cast<int4*>(sConvT + conv_off(ln, ks*8 + 4 + oh + o)) = lp;
        *reinterpret_cast<int4*>(gdst + o*16)      = hp;
        *reinterpret_cast<int4*>(gdst + 64 + o*16) = lp;
      }
    }
    __syncthreads();

    // MFMA tail: wave w -> node tile (w&3), nt pair {w>>2, (w>>2)+4}
    // (per-element accumulation order identical to k_uv: ks outer, hh/hl/lh/ll)
    f32x4 acc2[2];
    acc2[0] = f32x4{0.f, 0.f, 0.f, 0.f};
    acc2[1] = f32x4{0.f, 0.f, 0.f, 0.f};
    int nodeT = (w & 3)*16 + a15;
    int ntp = w >> 2;                      // 0..3
#pragma unroll
    for (int ks2 = 0; ks2 < 2; ++ks2) {
      short8 ah2 = *reinterpret_cast<const short8*>(sConvT + conv_off(nodeT, ks2*8 + g4));
      short8 al2 = *reinterpret_cast<const short8*>(sConvT + conv_off(nodeT, ks2*8 + 4 + g4));
#pragma unroll
      for (int q = 0; q < 2; ++q) {
        int nt = ntp + q*4;
        int fb = ((ks2*4 + g4)*8 + nt)*2;
        short8 bh = *reinterpret_cast<const short8*>(sBuf + fb*256 + a15*16);
        short8 bl = *reinterpret_cast<const short8*>(sBuf + (fb+1)*256 + a15*16);
        acc2[q] = __builtin_amdgcn_mfma_f32_16x16x32_bf16(ah2, bh, acc2[q], 0, 0, 0);
        acc2[q] = __builtin_amdgcn_mfma_f32_16x16x32_bf16(ah2, bl, acc2[q], 0, 0, 0);
        acc2[q] = __builtin_amdgcn_mfma_f32_16x16x32_bf16(al2, bh, acc2[q], 0, 0, 0);
        acc2[q] = __builtin_amdgcn_mfma_f32_16x16x32_bf16(al2, bl, acc2[q], 0, 0, 0);
      }
    }
    float bcv = bcN[ntp*16 + a15];
#pragma unroll
    for (int i = 0; i < 4; ++i) {
      size_t row = (size_t)gbase + rowBase + (w & 3)*16 + g4*4 + i;
      float p = acc2[0][i], q = acc2[1][i];
      Un[row*64 + ntp*16 + a15] = p - q + bcv;
      Vn[row*64 + ntp*16 + a15] = q;
    }
  }
}

extern "C" void kernel_launch(void* const* d_in, const int* in_sizes, int n_in,
                              void* d_out, int out_size, void* d_ws, size_t ws_size,
                              hipStream_t stream) {
  const float* x     = (const float*)d_in[0];
  const int*   batch = (const int*)d_in[1];
  const float* W1 = (const float*)d_in[2];
  const float* b1 = (const float*)d_in[3];
  const float* W2 = (const float*)d_in[4];
  const float* b2 = (const float*)d_in[5];
  const float* Wc[3] = {(const float*)d_in[6], (const float*)d_in[8], (const float*)d_in[10]};
  const float* bc[3] = {(const float*)d_in[7], (const float*)d_in[9], (const float*)d_in[11]};
  const float* Wo1 = (const float*)d_in[12];
  const float* bo1 = (const float*)d_in[13];
  const float* Wo2 = (const float*)d_in[14];
  const float* bo2 = (const float*)d_in[15];
  const float* Wo3 = (const float*)d_in[16];
  const float* bo3 = (const float*)d_in[17];

  float* outF = (float*)d_out;
  const size_t NEED = (size_t)(5*NN*64 + 2*NN)*4 + (size_t)2*NN*256 + 98304;

  if (ws_size >= NEED) {
    // fused path: ping-pong U/V/SQ/XB; k_uv only for layer 0
    float* ws = (float*)d_ws;
    float* F0  = ws;
    float* U0  = F0 + (size_t)NN*64;
    float* V0  = U0 + (size_t)NN*64;
    float* U1  = V0 + (size_t)NN*64;
    float* V1  = U1 + (size_t)NN*64;
    float* SQ0 = V1 + (size_t)NN*64;
    float* SQ1 = SQ0 + NN;
    unsigned char* XB0 = (unsigned char*)(SQ1 + NN);
    unsigned char* XB1 = XB0 + (size_t)NN*256;
    unsigned char* WfG = XB1 + (size_t)NN*256;

    k_mlp_in<<<NN/128 + 3, 256, 0, stream>>>(x, W1, b1, W2, b2, F0,
                                             Wc[0], Wc[1], Wc[2], WfG);
    k_uv<<<NN/64, 256, 0, stream>>>(F0, WfG, bc[0], U0, V0, SQ0, XB0);
    // l=0: read set0, tail writes set1 (layer-1 operands)
    k_knn<2><<<BG*(NPG/64), 1024, 0, stream>>>(XB0, SQ0, U0, V0, F0,
        Wo1, bo1, Wo2, bo2, Wo3, bo3, batch, outF, out_size,
        WfG + 32768, bc[1], U1, V1, SQ1, XB1);
    // l=1: read set1, tail writes set0 (layer-2 operands)
    k_knn<2><<<BG*(NPG/64), 1024, 0, stream>>>(XB1, SQ1, U1, V1, F0,
        Wo1, bo1, Wo2, bo2, Wo3, bo3, batch, outF, out_size,
        WfG + 65536, bc[2], U0, V0, SQ0, XB0);
    // l=2: read set0, fused output MLP
    k_knn<1><<<BG*(NPG/64), 1024, 0, stream>>>(XB0, SQ0, U0, V0, F0,
        Wo1, bo1, Wo2, bo2, Wo3, bo3, batch, outF, out_size,
        (const unsigned char*)0, (const float*)0,
        (float*)0, (float*)0, (float*)0, (unsigned char*)0);
  } else {
    // fallback: r15 schedule/layout (neutral safety path)
    float* ws = (float*)d_ws;
    float* F0 = ws;
    float* U  = ws + (size_t)NN*64;
    float* V  = ws + (size_t)2*NN*64;
    float* SQ = ws + (size_t)3*NN*64;
    unsigned char* XB = (unsigned char*)(SQ + NN);
    unsigned char* WfG = XB + (size_t)NN*256;

    k_mlp_in<<<NN/128 + 3, 256, 0, stream>>>(x, W1, b1, W2, b2, F0,
                                             Wc[0], Wc[1], Wc[2], WfG);
    for (int l = 0; l < 3; ++l) {
      k_uv<<<NN/64, 256, 0, stream>>>(F0, WfG + (size_t)l*32768, bc[l], U, V, SQ, XB);
      if (l < 2)
        k_knn<0><<<BG*(NPG/64), 1024, 0, stream>>>(XB, SQ, U, V, F0,
            Wo1, bo1, Wo2, bo2, Wo3, bo3, batch, outF, out_size,
            (const unsigned char*)0, (const float*)0,
            (float*)0, (float*)0, (float*)0, (unsigned char*)0);
      else
        k_knn<1><<<BG*(NPG/64), 1024, 0, stream>>>(XB, SQ, U, V, F0,
            Wo1, bo1, Wo2, bo2, Wo3, bo3, batch, outF, out_size,
            (const unsigned char*)0, (const float*)0,
            (float*)0, (float*)0, (float*)0, (unsigned char*)0);
    }
  }
}

// Round 17
// 251.547 us; speedup vs baseline: 1.5874x; 1.5874x over previous
//
#include <hip/hip_runtime.h>
#include <hip/hip_bf16.h>
#include <math.h>

#define NN   32768
#define BG   32
#define NPG  1024
#define HD   64
#define KK   24          // neighbors

#define FLTMAX 3.402823466e38f

typedef __attribute__((ext_vector_type(8))) short short8;
typedef __attribute__((ext_vector_type(4))) float f32x4;

__device__ __forceinline__ float elu1(float x) { return x > 0.f ? x : expm1f(x); }

__device__ __forceinline__ unsigned short f2bf(float x) {  // RNE to bf16
  unsigned u = __float_as_uint(x);
  unsigned r = (u + 0x7FFFu + ((u >> 16) & 1u)) >> 16;
  return (unsigned short)r;
}
__device__ __forceinline__ float bf2f(unsigned short h) {
  return __uint_as_float(((unsigned)h) << 16);
}
// monotone float -> uint order transform (finite values)
__device__ __forceinline__ unsigned ordf(float f) {
  unsigned b = __float_as_uint(f);
  return (b & 0x80000000u) ? ~b : (b | 0x80000000u);
}

// async global->LDS, 16B per lane; lds base must be wave-uniform (HW adds lane*16)
__device__ __forceinline__ void gl_lds16(const void* g, void* lds) {
  __builtin_amdgcn_global_load_lds(
      (const __attribute__((address_space(1))) unsigned int*)g,
      (__attribute__((address_space(3))) unsigned int*)lds, 16, 0, 0);
}

// ---------------- input MLP (+ folded-in Wc fragment conversion blocks) ----------------
__global__ void __launch_bounds__(256) k_mlp_in(
    const float* __restrict__ x, const float* __restrict__ W1, const float* __restrict__ b1,
    const float* __restrict__ W2, const float* __restrict__ b2, float* __restrict__ F,
    const float* __restrict__ Wc0, const float* __restrict__ Wc1,
    const float* __restrict__ Wc2, unsigned char* __restrict__ Wf) {
  __shared__ float sW1[8*64];
  __shared__ float sW2[64*64];
  __shared__ float sb1[64];
  __shared__ float sb2[64];
  int t = threadIdx.x;
  if (blockIdx.x >= NN/128) {
    int lb = blockIdx.x - NN/128;
    const float* Wc = lb == 0 ? Wc0 : (lb == 1 ? Wc1 : Wc2);
    unsigned char* dst = Wf + (size_t)lb*32768;
    int f = t >> 1, colHalf = t & 1;
    int part = f & 1, nt = (f >> 1) & 7, oct = (f >> 4) & 3, ks = f >> 6;
#pragma unroll
    for (int cc = 0; cc < 8; ++cc) {
      int c8 = colHalf*8 + cc;
      int dp = nt*16 + c8;
      const float* wsrc = (dp < 64) ? (Wc + dp) : (Wc + 64*64 + (dp - 64));
      unsigned short sh[8];
#pragma unroll
      for (int j = 0; j < 8; ++j) {
        float w = wsrc[(ks*32 + oct*8 + j)*64];
        unsigned short hi = f2bf(w);
        sh[j] = part ? f2bf(w - bf2f(hi)) : hi;
      }
      *reinterpret_cast<int4*>(dst + f*256 + c8*16) = make_int4(
          (unsigned)sh[0] | ((unsigned)sh[1] << 16), (unsigned)sh[2] | ((unsigned)sh[3] << 16),
          (unsigned)sh[4] | ((unsigned)sh[5] << 16), (unsigned)sh[6] | ((unsigned)sh[7] << 16));
    }
    return;
  }
  for (int i = t; i < 8*64; i += 256) sW1[i] = W1[i];
  for (int i = t; i < 64*64; i += 256) sW2[i] = W2[i];
  if (t < 64) { sb1[t] = b1[t]; sb2[t] = b2[t]; }
  __syncthreads();
  int node = blockIdx.x*128 + (t & 127);
  int half = t >> 7;
  float xr[8];
#pragma unroll
  for (int i = 0; i < 8; ++i) xr[i] = x[node*8 + i];
  float h1[64];
#pragma unroll 8
  for (int k = 0; k < 64; ++k) {
    float a = sb1[k];
#pragma unroll
    for (int i = 0; i < 8; ++i) a += xr[i]*sW1[i*64+k];
    h1[k] = elu1(a);
  }
#pragma unroll 2
  for (int dd = 0; dd < 32; ++dd) {
    int d = half*32 + dd;
    float a = sb2[d];
#pragma unroll
    for (int k = 0; k < 64; ++k) a += h1[k]*sW2[k*64+d];
    F[node*64 + d] = elu1(a);
  }
}

// split-bf16 conv-buffer addressing
__device__ __forceinline__ int conv_off(int node, int g) {
  return node*256 + ((((g & 7) ^ (node & 7)) | (g & 8)) << 4);
}

// ---- per-layer (MFMA): U = X@(A-B)+bc, V = X@B (fp32), SQ, XB = split-bf16(X) ----
// (UNCHANGED from r13/r14/r15 — passed at absmax 0.265625.)
__global__ void __launch_bounds__(256) k_uv(
    const float* __restrict__ X, const unsigned char* __restrict__ Wf,
    const float* __restrict__ bc,
    float* __restrict__ U, float* __restrict__ V, float* __restrict__ SQ,
    unsigned char* __restrict__ XB) {
  __shared__ __align__(16) unsigned char sConv[64*256];
  __shared__ __align__(16) unsigned char sWf[128*256];
  __shared__ float sbc[64];
  int t = threadIdx.x;
  const int lane = t & 63, wave = t >> 6;
  const int g4 = lane >> 4, a15 = lane & 15;
  int b = blockIdx.x;
  int graph = (b & 7) + 8*(b >> 7);
  int nig0 = ((b >> 3) & 15) * 64;
  int base = graph*1024 + nig0;

  if (t < 64) sbc[t] = bc[t];

#pragma unroll
  for (int i = 0; i < 8; ++i) {
    int I = wave*8 + i;
    gl_lds16(Wf + (size_t)I*1024 + lane*16, (void*)(sWf + I*1024));
  }

  {
    int ln = t >> 2, q2 = t & 3;
    int ks = q2 >> 1, oh = (q2 & 1) * 2;
    const float* src = X + (size_t)(base + ln)*64 + ks*32 + oh*8;
    unsigned hu[8], lu[8];
    float sq = 0.f;
#pragma unroll
    for (int q = 0; q < 4; ++q) {
      float4 f = *reinterpret_cast<const float4*>(src + q*4);
      sq += f.x*f.x + f.y*f.y + f.z*f.z + f.w*f.w;
      unsigned short h0 = f2bf(f.x), h1 = f2bf(f.y), h2 = f2bf(f.z), h3 = f2bf(f.w);
      unsigned short l0 = f2bf(f.x - bf2f(h0)), l1 = f2bf(f.y - bf2f(h1));
      unsigned short l2 = f2bf(f.z - bf2f(h2)), l3 = f2bf(f.w - bf2f(h3));
      hu[q*2]   = (unsigned)h0 | ((unsigned)h1 << 16);
      hu[q*2+1] = (unsigned)h2 | ((unsigned)h3 << 16);
      lu[q*2]   = (unsigned)l0 | ((unsigned)l1 << 16);
      lu[q*2+1] = (unsigned)l2 | ((unsigned)l3 << 16);
    }
    sq += __shfl_xor(sq, 1);
    sq += __shfl_xor(sq, 2);
    if (q2 == 0) SQ[base + ln] = sq;
    unsigned char* gdst = XB + (((size_t)graph*2 + ks)*1024 + nig0 + ln)*128 + oh*16;
#pragma unroll
    for (int o = 0; o < 2; ++o) {
      int4 hp = make_int4(hu[o*4], hu[o*4+1], hu[o*4+2], hu[o*4+3]);
      int4 lp = make_int4(lu[o*4], lu[o*4+1], lu[o*4+2], lu[o*4+3]);
      *reinterpret_cast<int4*>(sConv + conv_off(ln, ks*8 + oh + o))     = hp;
      *reinterpret_cast<int4*>(sConv + conv_off(ln, ks*8 + 4 + oh + o)) = lp;
      *reinterpret_cast<int4*>(gdst + o*16)      = hp;
      *reinterpret_cast<int4*>(gdst + 64 + o*16) = lp;
    }
  }
  __syncthreads();

  f32x4 acc[8];
#pragma unroll
  for (int n = 0; n < 8; ++n) acc[n] = f32x4{0.f, 0.f, 0.f, 0.f};
#pragma unroll
  for (int ks = 0; ks < 2; ++ks) {
    int node = wave*16 + a15;
    short8 ah = *reinterpret_cast<const short8*>(sConv + conv_off(node, ks*8 + g4));
    short8 al = *reinterpret_cast<const short8*>(sConv + conv_off(node, ks*8 + 4 + g4));
#pragma unroll
    for (int nt = 0; nt < 8; ++nt) {
      int fb = ((ks*4 + g4)*8 + nt)*2;
      short8 bh = *reinterpret_cast<const short8*>(sWf + fb*256 + a15*16);
      short8 bl = *reinterpret_cast<const short8*>(sWf + (fb+1)*256 + a15*16);
      acc[nt] = __builtin_amdgcn_mfma_f32_16x16x32_bf16(ah, bh, acc[nt], 0, 0, 0);
      acc[nt] = __builtin_amdgcn_mfma_f32_16x16x32_bf16(ah, bl, acc[nt], 0, 0, 0);
      acc[nt] = __builtin_amdgcn_mfma_f32_16x16x32_bf16(al, bh, acc[nt], 0, 0, 0);
      acc[nt] = __builtin_amdgcn_mfma_f32_16x16x32_bf16(al, bl, acc[nt], 0, 0, 0);
    }
  }

#pragma unroll
  for (int nt = 0; nt < 4; ++nt) {
    float bcv = sbc[nt*16 + a15];
#pragma unroll
    for (int i = 0; i < 4; ++i) {
      size_t row = base + wave*16 + g4*4 + i;
      float p = acc[nt][i], q = acc[nt+4][i];
      U[row*64 + nt*16 + a15] = p - q + bcv;
      V[row*64 + nt*16 + a15] = q;
    }
  }
}

// read-side LDS addressing for staged columns
__device__ __forceinline__ int col_byte(int node, int granule) {
  return node*128 + ((granule ^ (node & 7)) << 4);
}

// ------- knn + fused aggregate. 1024 thr / 16 waves / 64 rows per block.
// MODE 0: plain (aggregate -> F).  MODE 1: last (fused output MLP, r15-verified).
// MODE 2: fused next-layer k_uv tail (writes Un/Vn/SQn/XBn from new F rows).
// r17: NO min-waves clamp (r16's __launch_bounds__(1024,8) capped VGPR at 64 ->
// spills -> 276 MB scratch writes; compiler-chosen allocation restores regs).
template<int MODE>
__global__ void __launch_bounds__(1024) k_knn(
    const unsigned char* __restrict__ XB, const float* __restrict__ SQ,
    const float* __restrict__ U, const float* __restrict__ V,
    float* __restrict__ F,
    const float* __restrict__ Wo1, const float* __restrict__ bo1,
    const float* __restrict__ Wo2, const float* __restrict__ bo2,
    const float* __restrict__ Wo3, const float* __restrict__ bo3,
    const int* __restrict__ batch, float* __restrict__ out, int out_size,
    const unsigned char* __restrict__ WfN, const float* __restrict__ bcN,
    float* __restrict__ Un, float* __restrict__ Vn, float* __restrict__ SQn,
    unsigned char* __restrict__ XBn) {
  __shared__ __align__(16) unsigned char sBuf[49152];    // dbuf -> dist -> sCmp -> tail bufs
  __shared__ __align__(16) unsigned char sRowB[64*272];  // rows -> (tail) new-F rows
  __shared__ float sCsq[1024];
  __shared__ int nIdx[64*KK];

  int b = blockIdx.x;
  int g = (b & 7) + 8*(b >> 7);          // graph -> XCD g%8 (512 blocks)
  int rowBase = ((b >> 3) & 15) * 64;
  int gbase = g * NPG;
  int t = threadIdx.x;
  const int lane = t & 63, w = t >> 6;
  const int g4 = lane >> 4, a15 = lane & 15;
  const int rg = w >> 2, wc = w & 3;

  // ---- stage 64 row fragments + column squared norms ----
  {
    int row = t >> 4, part = t & 15;
    int ks = part >> 3, o = part & 7;
    const unsigned char* src =
        XB + (((size_t)g*2 + ks)*1024 + rowBase + row)*128 + o*16;
    *reinterpret_cast<int4*>(sRowB + row*272 + part*16) =
        *reinterpret_cast<const int4*>(src);
    if (t < 256) {
      float4 q = *reinterpret_cast<const float4*>(SQ + gbase + t*4);
      *reinterpret_cast<float4*>(sCsq + t*4) = q;
    }
  }
  // prologue: stage chunks 0,1 into bufs 0,1
  {
    int n = t >> 3, gq = t & 7;
    int srcChunk = (n << 3) + (gq ^ (n & 7));
    const unsigned char* sl0 = XB + (((size_t)g*2 + 0)*1024)*128;
    gl_lds16(sl0 + (size_t)srcChunk*16, (void*)(sBuf + 0*16384 + w*1024));
    const unsigned char* sl1 = XB + (((size_t)g*2 + 1)*1024)*128;
    gl_lds16(sl1 + (size_t)srcChunk*16, (void*)(sBuf + 1*16384 + w*1024));
  }
  __syncthreads();

  short8 ahf[2], alf[2];
#pragma unroll
  for (int ks = 0; ks < 2; ++ks) {
    ahf[ks] = *reinterpret_cast<const short8*>(
        sRowB + (rg*16 + a15)*272 + ks*128 + (g4 << 4));
    alf[ks] = *reinterpret_cast<const short8*>(
        sRowB + (rg*16 + a15)*272 + ks*128 + 64 + (g4 << 4));
  }

  f32x4 acc[16];
#pragma unroll
  for (int i = 0; i < 16; ++i) acc[i] = f32x4{0.f, 0.f, 0.f, 0.f};

  // ---- Gram over 16 chunks, 2-deep prefetch, counted vmcnt ----
#pragma unroll
  for (int c = 0; c < 16; ++c) {
    if (c) {
      if (c < 15) asm volatile("s_waitcnt vmcnt(1)" ::: "memory");
      else        asm volatile("s_waitcnt vmcnt(0)" ::: "memory");
      __builtin_amdgcn_sched_barrier(0);
      __builtin_amdgcn_s_barrier();
    }
    if (c < 14) {
      int cn = c + 2;
      const unsigned char* sl =
          XB + (((size_t)g*2 + (cn & 1))*1024 + (cn >> 1)*128)*128;
      int n = t >> 3, gq = t & 7;
      int srcChunk = (n << 3) + (gq ^ (n & 7));
      gl_lds16(sl + (size_t)srcChunk*16, (void*)(sBuf + (cn % 3)*16384 + w*1024));
    }
    const unsigned char* bufc = sBuf + (c % 3)*16384;
    short8 ah = ahf[c & 1], al = alf[c & 1];
#pragma unroll
    for (int tt = 0; tt < 2; ++tt) {
      int node = wc*32 + tt*16 + a15;
      short8 bh = *reinterpret_cast<const short8*>(bufc + col_byte(node, g4));
      short8 bl = *reinterpret_cast<const short8*>(bufc + col_byte(node, 4 + g4));
      int ai = (c >> 1)*2 + tt;
      acc[ai] = __builtin_amdgcn_mfma_f32_16x16x32_bf16(ah, bh, acc[ai], 0, 0, 0);
      acc[ai] = __builtin_amdgcn_mfma_f32_16x16x32_bf16(ah, bl, acc[ai], 0, 0, 0);
      acc[ai] = __builtin_amdgcn_mfma_f32_16x16x32_bf16(al, bh, acc[ai], 0, 0, 0);
      acc[ai] = __builtin_amdgcn_mfma_f32_16x16x32_bf16(al, bl, acc[ai], 0, 0, 0);
    }
  }

  // ---- transpose acc -> per-wave selection regs (r12 geometry) ----
  float v[4][16];
  float* dL = (float*)sBuf;
#pragma unroll
  for (int e = 0; e < 8; ++e) {
    __syncthreads();
#pragma unroll
    for (int k2 = 0; k2 < 2; ++k2) {
      int ai = e*2 + k2;
      int lc = wc*32 + k2*16 + a15;
      float cs = sCsq[e*128 + lc];
#pragma unroll
      for (int i = 0; i < 4; ++i) {
        int r64 = rg*16 + g4*4 + i;
        dL[r64*128 + (lc ^ (((r64 >> 2) & 3) << 3))] = cs - 2.0f*acc[ai][i];
      }
    }
    __syncthreads();
#pragma unroll
    for (int m2 = 0; m2 < 2; ++m2)
#pragma unroll
      for (int r = 0; r < 4; ++r) {
        int rr = w*4 + r;
        v[r][e*2 + m2] = dL[rr*128 + ((m2*64 + lane) ^ (((rr >> 2) & 3) << 3))];
      }
  }
  __syncthreads();

  unsigned long long* sCmp = (unsigned long long*)sBuf;
  const unsigned long long mlt = (1ull << lane) - 1ull;

  unsigned uu[4];
#pragma unroll
  for (int r = 0; r < 4; ++r) {
    float bm = v[r][0];
#pragma unroll
    for (int m = 1; m < 16; ++m) bm = fminf(bm, v[r][m]);
    uu[r] = ordf(bm);
  }

  unsigned pp[4] = {0u, 0u, 0u, 0u};
#pragma unroll
  for (int bb = 31; bb >= 0; --bb) {
#pragma unroll
    for (int r = 0; r < 4; ++r) {
      unsigned q = pp[r] | (1u << bb);
      if ((int)__popcll(__ballot(uu[r] < q)) < KK) pp[r] = q;
    }
  }

  int total[4];
#pragma unroll
  for (int r = 0; r < 4; ++r) {
    int base = 0;
#pragma unroll
    for (int m = 0; m < 16; ++m) {
      unsigned ov = ordf(v[r][m]);
      bool f = ov <= pp[r];
      unsigned long long bal = __ballot(f);
      int slot = base + (int)__popcll(bal & mlt);
      if (f && slot < 64)
        sCmp[(w*4 + r)*64 + slot] =
            ((unsigned long long)ov << 32) | (unsigned)(lane + (m << 6));
      base += (int)__popcll(bal);
    }
    total[r] = base;
  }

  unsigned cu2[4]; int col2[4];
#pragma unroll
  for (int r = 0; r < 4; ++r) {
    unsigned long long kp = (lane < total[r]) ? sCmp[(w*4 + r)*64 + lane] : ~0ull;
    cu2[r] = (unsigned)(kp >> 32);
    col2[r] = (int)(unsigned)(kp & 0xFFFFFFFFull);
  }

  if (MODE == 2) {
    // sCmp consumed; stage next-layer W fragments (32 KB) into sBuf[0..32768)
    __syncthreads();
#pragma unroll
    for (int i = 0; i < 2; ++i) {
      int I = w*2 + i;
      gl_lds16(WfN + (size_t)I*1024 + lane*16, (void*)(sBuf + I*1024));
    }
  }

  unsigned p2[4] = {0u, 0u, 0u, 0u};
#pragma unroll
  for (int bb = 31; bb >= 0; --bb) {
#pragma unroll
    for (int r = 0; r < 4; ++r) {
      unsigned q = p2[r] | (1u << bb);
      if ((int)__popcll(__ballot(cu2[r] < q)) < KK) p2[r] = q;
    }
  }
  int need[4]; bool tie[4];
#pragma unroll
  for (int r = 0; r < 4; ++r) {
    need[r] = KK - (int)__popcll(__ballot(cu2[r] < p2[r]));
    tie[r] = (cu2[r] == p2[r]);
  }
  unsigned p3[4] = {0u, 0u, 0u, 0u};
#pragma unroll
  for (int bb = 9; bb >= 0; --bb) {
#pragma unroll
    for (int r = 0; r < 4; ++r) {
      unsigned q = p3[r] | (1u << bb);
      if ((int)__popcll(__ballot(tie[r] && ((unsigned)col2[r] < q))) < need[r]) p3[r] = q;
    }
  }

  bool allfast = total[0] <= 64 && total[1] <= 64 && total[2] <= 64 && total[3] <= 64;
  if (allfast) {
#pragma unroll
    for (int r = 0; r < 4; ++r) {
      bool in24 = (cu2[r] < p2[r]) || (tie[r] && ((unsigned)col2[r] <= p3[r]));
      unsigned long long ball = __ballot(in24);
      int pos = (int)__popcll(ball & mlt);
      if (in24) nIdx[(w*4 + r)*KK + pos] = col2[r];
    }
  } else {
#pragma unroll
    for (int r = 0; r < 4; ++r) {
      unsigned selm = 0;
      for (int it = 0; it < KK; ++it) {
        float bv = FLTMAX; int bj = 0x7fffffff;
#pragma unroll
        for (int m = 0; m < 16; ++m) {
          float vv = ((selm >> m) & 1) ? FLTMAX : v[r][m];
          int col = lane + (m << 6);
          bool bsel = vv < bv; bv = bsel ? vv : bv; bj = bsel ? col : bj;
        }
#pragma unroll
        for (int s = 32; s; s >>= 1) {
          float ov = __shfl_xor(bv, s); int oj = __shfl_xor(bj, s);
          bool bsel = (ov < bv) || (ov == bv && oj < bj);
          bv = bsel ? ov : bv; bj = bsel ? oj : bj;
        }
        if (lane == (bj & 63)) selm |= 1u << (bj >> 6);
        if (lane == 0) nIdx[(w*4 + r)*KK + it] = bj;
      }
    }
  }

  // ---- fused aggregate ----
  if (MODE == 0) {
#pragma unroll
    for (int r = 0; r < 4; ++r) {
      int row = rowBase + w*4 + r;
      float mx = -FLTMAX;
#pragma unroll
      for (int tt = 0; tt < KK; ++tt) {
        int j = nIdx[(w*4 + r)*KK + tt];
        mx = fmaxf(mx, V[((size_t)(gbase + j))*64 + lane]);
      }
      size_t off = (size_t)(gbase + row)*64 + lane;
      F[off] += elu1(U[off] + mx);
    }
  } else if (MODE == 1) {
    // rows -> LDS, then fused output MLP (r15-verified, bit-identical to k_out)
    float* sOutF = (float*)sRowB;              // [64][68]
#pragma unroll
    for (int r = 0; r < 4; ++r) {
      int row = rowBase + w*4 + r;
      float mx = -FLTMAX;
#pragma unroll
      for (int tt = 0; tt < KK; ++tt) {
        int j = nIdx[(w*4 + r)*KK + tt];
        mx = fmaxf(mx, V[((size_t)(gbase + j))*64 + lane]);
      }
      size_t off = (size_t)(gbase + row)*64 + lane;
      sOutF[(w*4 + r)*68 + lane] = F[off] + elu1(U[off] + mx);
    }
    __syncthreads();

    float* sW1o = (float*)sBuf;
    float* sW2o = sW1o + 64*64;
    float* sW3o = sW2o + 64*32;
    float* sB1o = sW3o + 32*8;
    float* sB2o = sB1o + 64;
    float* sB3o = sB2o + 32;
    float* sO1  = sB3o + 8;
    for (int i = t; i < 64*64; i += 1024) sW1o[i] = Wo1[i];
    for (int i = t; i < 64*32; i += 1024) sW2o[i] = Wo2[i];
    if (t < 256) sW3o[t] = Wo3[t];
    if (t < 64) sB1o[t] = bo1[t];
    if (t < 32) sB2o[t] = bo2[t];
    if (t < 8)  sB3o[t] = bo3[t];
    __syncthreads();

    int ln = t >> 3, qd = t & 7;
    if (t < 512) {
      float a1[8];
#pragma unroll
      for (int dd = 0; dd < 8; ++dd) a1[dd] = sB1o[qd*8 + dd];
#pragma unroll 4
      for (int k = 0; k < 64; ++k) {
        float fk = sOutF[ln*68 + k];
#pragma unroll
        for (int dd = 0; dd < 8; ++dd) a1[dd] += fk*sW1o[k*64 + qd*8 + dd];
      }
#pragma unroll
      for (int dd = 0; dd < 8; ++dd) sO1[ln*65 + qd*8 + dd] = elu1(a1[dd]);
    }
    __syncthreads();

    float* sO2 = (float*)sRowB;
    if (t < 512) {
      float a2[4];
#pragma unroll
      for (int dd = 0; dd < 4; ++dd) a2[dd] = sB2o[qd*4 + dd];
#pragma unroll 4
      for (int k = 0; k < 64; ++k) {
        float ok = sO1[ln*65 + k];
#pragma unroll
        for (int dd = 0; dd < 4; ++dd) a2[dd] += ok*sW2o[k*32 + qd*4 + dd];
      }
#pragma unroll
      for (int dd = 0; dd < 4; ++dd) sO2[ln*34 + qd*4 + dd] = elu1(a2[dd]);
    }
    __syncthreads();

    if (t < 512) {
      int nodeG = gbase + rowBase + ln;
      float a3 = sB3o[qd];
#pragma unroll
      for (int k = 0; k < 32; ++k) a3 += sO2[ln*34 + k]*sW3o[k*8 + qd];
      out[(size_t)nodeG*8 + qd] = a3;
      if (qd == 0 && out_size >= NN*9) out[(size_t)NN*8 + nodeG] = (float)batch[nodeG];
    }
  } else {
    // MODE 2: aggregate -> F global + LDS, then fused next-layer k_uv tail
    float* sOutF = (float*)sRowB;              // [64][68]
#pragma unroll
    for (int r = 0; r < 4; ++r) {
      int row = rowBase + w*4 + r;
      float mx = -FLTMAX;
#pragma unroll
      for (int tt = 0; tt < KK; ++tt) {
        int j = nIdx[(w*4 + r)*KK + tt];
        mx = fmaxf(mx, V[((size_t)(gbase + j))*64 + lane]);
      }
      size_t off = (size_t)(gbase + row)*64 + lane;
      float nf = F[off] + elu1(U[off] + mx);
      F[off] = nf;
      sOutF[(w*4 + r)*68 + lane] = nf;
    }
    asm volatile("s_waitcnt vmcnt(0)" ::: "memory");   // WfN staging done
    __builtin_amdgcn_sched_barrier(0);
    __syncthreads();                                    // sOutF complete block-wide

    // conversion: EXACT k_uv phase-A code on threads t<256 (same mapping ->
    // bit-identical SQ/XB), source = sOutF LDS, sConv target = sBuf[32K..48K)
    unsigned char* sConvT = sBuf + 32768;
    if (t < 256) {
      int ln = t >> 2, q2 = t & 3;
      int ks = q2 >> 1, oh = (q2 & 1) * 2;
      const float* src = sOutF + ln*68 + ks*32 + oh*8;
      unsigned hu[8], lu[8];
      float sq = 0.f;
#pragma unroll
      for (int q = 0; q < 4; ++q) {
        float4 f = *reinterpret_cast<const float4*>(src + q*4);
        sq += f.x*f.x + f.y*f.y + f.z*f.z + f.w*f.w;
        unsigned short h0 = f2bf(f.x), h1 = f2bf(f.y), h2 = f2bf(f.z), h3 = f2bf(f.w);
        unsigned short l0 = f2bf(f.x - bf2f(h0)), l1 = f2bf(f.y - bf2f(h1));
        unsigned short l2 = f2bf(f.z - bf2f(h2)), l3 = f2bf(f.w - bf2f(h3));
        hu[q*2]   = (unsigned)h0 | ((unsigned)h1 << 16);
        hu[q*2+1] = (unsigned)h2 | ((unsigned)h3 << 16);
        lu[q*2]   = (unsigned)l0 | ((unsigned)l1 << 16);
        lu[q*2+1] = (unsigned)l2 | ((unsigned)l3 << 16);
      }
      sq += __shfl_xor(sq, 1);
      sq += __shfl_xor(sq, 2);
      if (q2 == 0) SQn[gbase + rowBase + ln] = sq;
      unsigned char* gdst = XBn + (((size_t)g*2 + ks)*1024 + rowBase + ln)*128 + oh*16;
#pragma unroll
      for (int o = 0; o < 2; ++o) {
        int4 hp = make_int4(hu[o*4], hu[o*4+1], hu[o*4+2], hu[o*4+3]);
        int4 lp = make_int4(lu[o*4], lu[o*4+1], lu[o*4+2], lu[o*4+3]);
        *reinterpret_cast<int4*>(sConvT + conv_off(ln, ks*8 + oh + o))     = hp;
        *reinterpret_cast<int4*>(sConvT + conv_off(ln, ks*8 + 4 + oh + o)) = lp;
        *reinterpret_cast<int4*>(gdst + o*16)      = hp;
        *reinterpret_cast<int4*>(gdst + 64 + o*16) = lp;
      }
    }
    __syncthreads();

    // MFMA tail: wave w -> node tile (w&3), nt pair {w>>2, (w>>2)+4}
    // (per-element accumulation order identical to k_uv: ks outer, hh/hl/lh/ll)
    f32x4 acc2[2];
    acc2[0] = f32x4{0.f, 0.f, 0.f, 0.f};
    acc2[1] = f32x4{0.f, 0.f, 0.f, 0.f};
    int nodeT = (w & 3)*16 + a15;
    int ntp = w >> 2;                      // 0..3
#pragma unroll
    for (int ks2 = 0; ks2 < 2; ++ks2) {
      short8 ah2 = *reinterpret_cast<const short8*>(sConvT + conv_off(nodeT, ks2*8 + g4));
      short8 al2 = *reinterpret_cast<const short8*>(sConvT + conv_off(nodeT, ks2*8 + 4 + g4));
#pragma unroll
      for (int q = 0; q < 2; ++q) {
        int nt = ntp + q*4;
        int fb = ((ks2*4 + g4)*8 + nt)*2;
        short8 bh = *reinterpret_cast<const short8*>(sBuf + fb*256 + a15*16);
        short8 bl = *reinterpret_cast<const short8*>(sBuf + (fb+1)*256 + a15*16);
        acc2[q] = __builtin_amdgcn_mfma_f32_16x16x32_bf16(ah2, bh, acc2[q], 0, 0, 0);
        acc2[q] = __builtin_amdgcn_mfma_f32_16x16x32_bf16(ah2, bl, acc2[q], 0, 0, 0);
        acc2[q] = __builtin_amdgcn_mfma_f32_16x16x32_bf16(al2, bh, acc2[q], 0, 0, 0);
        acc2[q] = __builtin_amdgcn_mfma_f32_16x16x32_bf16(al2, bl, acc2[q], 0, 0, 0);
      }
    }
    float bcv = bcN[ntp*16 + a15];
#pragma unroll
    for (int i = 0; i < 4; ++i) {
      size_t row = (size_t)gbase + rowBase + (w & 3)*16 + g4*4 + i;
      float p = acc2[0][i], q = acc2[1][i];
      Un[row*64 + ntp*16 + a15] = p - q + bcv;
      Vn[row*64 + ntp*16 + a15] = q;
    }
  }
}

extern "C" void kernel_launch(void* const* d_in, const int* in_sizes, int n_in,
                              void* d_out, int out_size, void* d_ws, size_t ws_size,
                              hipStream_t stream) {
  const float* x     = (const float*)d_in[0];
  const int*   batch = (const int*)d_in[1];
  const float* W1 = (const float*)d_in[2];
  const float* b1 = (const float*)d_in[3];
  const float* W2 = (const float*)d_in[4];
  const float* b2 = (const float*)d_in[5];
  const float* Wc[3] = {(const float*)d_in[6], (const float*)d_in[8], (const float*)d_in[10]};
  const float* bc[3] = {(const float*)d_in[7], (const float*)d_in[9], (const float*)d_in[11]};
  const float* Wo1 = (const float*)d_in[12];
  const float* bo1 = (const float*)d_in[13];
  const float* Wo2 = (const float*)d_in[14];
  const float* bo2 = (const float*)d_in[15];
  const float* Wo3 = (const float*)d_in[16];
  const float* bo3 = (const float*)d_in[17];

  float* outF = (float*)d_out;
  const size_t NEED = (size_t)(5*NN*64 + 2*NN)*4 + (size_t)2*NN*256 + 98304;

  if (ws_size >= NEED) {
    // fused path: ping-pong U/V/SQ/XB; k_uv only for layer 0
    float* ws = (float*)d_ws;
    float* F0  = ws;
    float* U0  = F0 + (size_t)NN*64;
    float* V0  = U0 + (size_t)NN*64;
    float* U1  = V0 + (size_t)NN*64;
    float* V1  = U1 + (size_t)NN*64;
    float* SQ0 = V1 + (size_t)NN*64;
    float* SQ1 = SQ0 + NN;
    unsigned char* XB0 = (unsigned char*)(SQ1 + NN);
    unsigned char* XB1 = XB0 + (size_t)NN*256;
    unsigned char* WfG = XB1 + (size_t)NN*256;

    k_mlp_in<<<NN/128 + 3, 256, 0, stream>>>(x, W1, b1, W2, b2, F0,
                                             Wc[0], Wc[1], Wc[2], WfG);
    k_uv<<<NN/64, 256, 0, stream>>>(F0, WfG, bc[0], U0, V0, SQ0, XB0);
    // l=0: read set0, tail writes set1 (layer-1 operands)
    k_knn<2><<<BG*(NPG/64), 1024, 0, stream>>>(XB0, SQ0, U0, V0, F0,
        Wo1, bo1, Wo2, bo2, Wo3, bo3, batch, outF, out_size,
        WfG + 32768, bc[1], U1, V1, SQ1, XB1);
    // l=1: read set1, tail writes set0 (layer-2 operands)
    k_knn<2><<<BG*(NPG/64), 1024, 0, stream>>>(XB1, SQ1, U1, V1, F0,
        Wo1, bo1, Wo2, bo2, Wo3, bo3, batch, outF, out_size,
        WfG + 65536, bc[2], U0, V0, SQ0, XB0);
    // l=2: read set0, fused output MLP
    k_knn<1><<<BG*(NPG/64), 1024, 0, stream>>>(XB0, SQ0, U0, V0, F0,
        Wo1, bo1, Wo2, bo2, Wo3, bo3, batch, outF, out_size,
        (const unsigned char*)0, (const float*)0,
        (float*)0, (float*)0, (float*)0, (unsigned char*)0);
  } else {
    // fallback: r15 schedule/layout (neutral safety path)
    float* ws = (float*)d_ws;
    float* F0 = ws;
    float* U  = ws + (size_t)NN*64;
    float* V  = ws + (size_t)2*NN*64;
    float* SQ = ws + (size_t)3*NN*64;
    unsigned char* XB = (unsigned char*)(SQ + NN);
    unsigned char* WfG = XB + (size_t)NN*256;

    k_mlp_in<<<NN/128 + 3, 256, 0, stream>>>(x, W1, b1, W2, b2, F0,
                                             Wc[0], Wc[1], Wc[2], WfG);
    for (int l = 0; l < 3; ++l) {
      k_uv<<<NN/64, 256, 0, stream>>>(F0, WfG + (size_t)l*32768, bc[l], U, V, SQ, XB);
      if (l < 2)
        k_knn<0><<<BG*(NPG/64), 1024, 0, stream>>>(XB, SQ, U, V, F0,
            Wo1, bo1, Wo2, bo2, Wo3, bo3, batch, outF, out_size,
            (const unsigned char*)0, (const float*)0,
            (float*)0, (float*)0, (float*)0, (unsigned char*)0);
      else
        k_knn<1><<<BG*(NPG/64), 1024, 0, stream>>>(XB, SQ, U, V, F0,
            Wo1, bo1, Wo2, bo2, Wo3, bo3, batch, outF, out_size,
            (const unsigned char*)0, (const float*)0,
            (float*)0, (float*)0, (float*)0, (unsigned char*)0);
    }
  }
}

// Round 18
// 228.504 us; speedup vs baseline: 1.7475x; 1.1008x over previous
//
#include <hip/hip_runtime.h>
#include <hip/hip_bf16.h>
#include <math.h>

#define NN   32768
#define BG   32
#define NPG  1024
#define HD   64
#define KK   24          // neighbors

#define FLTMAX 3.402823466e38f

typedef __attribute__((ext_vector_type(8))) short short8;
typedef __attribute__((ext_vector_type(4))) float f32x4;

__device__ __forceinline__ float elu1(float x) { return x > 0.f ? x : expm1f(x); }

__device__ __forceinline__ unsigned short f2bf(float x) {  // RNE to bf16
  unsigned u = __float_as_uint(x);
  unsigned r = (u + 0x7FFFu + ((u >> 16) & 1u)) >> 16;
  return (unsigned short)r;
}
__device__ __forceinline__ float bf2f(unsigned short h) {
  return __uint_as_float(((unsigned)h) << 16);
}
// monotone float -> uint order transform (finite values)
__device__ __forceinline__ unsigned ordf(float f) {
  unsigned b = __float_as_uint(f);
  return (b & 0x80000000u) ? ~b : (b | 0x80000000u);
}

// async global->LDS, 16B per lane; lds base must be wave-uniform (HW adds lane*16)
__device__ __forceinline__ void gl_lds16(const void* g, void* lds) {
  __builtin_amdgcn_global_load_lds(
      (const __attribute__((address_space(1))) unsigned int*)g,
      (__attribute__((address_space(3))) unsigned int*)lds, 16, 0, 0);
}

// ---------------- input MLP (+ folded-in Wc fragment conversion blocks) ----------------
__global__ void __launch_bounds__(256) k_mlp_in(
    const float* __restrict__ x, const float* __restrict__ W1, const float* __restrict__ b1,
    const float* __restrict__ W2, const float* __restrict__ b2, float* __restrict__ F,
    const float* __restrict__ Wc0, const float* __restrict__ Wc1,
    const float* __restrict__ Wc2, unsigned char* __restrict__ Wf) {
  __shared__ float sW1[8*64];
  __shared__ float sW2[64*64];
  __shared__ float sb1[64];
  __shared__ float sb2[64];
  int t = threadIdx.x;
  if (blockIdx.x >= NN/128) {
    int lb = blockIdx.x - NN/128;
    const float* Wc = lb == 0 ? Wc0 : (lb == 1 ? Wc1 : Wc2);
    unsigned char* dst = Wf + (size_t)lb*32768;
    int f = t >> 1, colHalf = t & 1;
    int part = f & 1, nt = (f >> 1) & 7, oct = (f >> 4) & 3, ks = f >> 6;
#pragma unroll
    for (int cc = 0; cc < 8; ++cc) {
      int c8 = colHalf*8 + cc;
      int dp = nt*16 + c8;
      const float* wsrc = (dp < 64) ? (Wc + dp) : (Wc + 64*64 + (dp - 64));
      unsigned short sh[8];
#pragma unroll
      for (int j = 0; j < 8; ++j) {
        float w = wsrc[(ks*32 + oct*8 + j)*64];
        unsigned short hi = f2bf(w);
        sh[j] = part ? f2bf(w - bf2f(hi)) : hi;
      }
      *reinterpret_cast<int4*>(dst + f*256 + c8*16) = make_int4(
          (unsigned)sh[0] | ((unsigned)sh[1] << 16), (unsigned)sh[2] | ((unsigned)sh[3] << 16),
          (unsigned)sh[4] | ((unsigned)sh[5] << 16), (unsigned)sh[6] | ((unsigned)sh[7] << 16));
    }
    return;
  }
  for (int i = t; i < 8*64; i += 256) sW1[i] = W1[i];
  for (int i = t; i < 64*64; i += 256) sW2[i] = W2[i];
  if (t < 64) { sb1[t] = b1[t]; sb2[t] = b2[t]; }
  __syncthreads();
  int node = blockIdx.x*128 + (t & 127);
  int half = t >> 7;
  float xr[8];
#pragma unroll
  for (int i = 0; i < 8; ++i) xr[i] = x[node*8 + i];
  float h1[64];
#pragma unroll 8
  for (int k = 0; k < 64; ++k) {
    float a = sb1[k];
#pragma unroll
    for (int i = 0; i < 8; ++i) a += xr[i]*sW1[i*64+k];
    h1[k] = elu1(a);
  }
#pragma unroll 2
  for (int dd = 0; dd < 32; ++dd) {
    int d = half*32 + dd;
    float a = sb2[d];
#pragma unroll
    for (int k = 0; k < 64; ++k) a += h1[k]*sW2[k*64+d];
    F[node*64 + d] = elu1(a);
  }
}

// split-bf16 conv-buffer addressing
__device__ __forceinline__ int conv_off(int node, int g) {
  return node*256 + ((((g & 7) ^ (node & 7)) | (g & 8)) << 4);
}

// ---- per-layer (MFMA): U = X@(A-B)+bc, V = X@B (fp32), SQ, XB = split-bf16(X) ----
// (UNCHANGED from r13..r17 — passed at absmax 0.265625.)
__global__ void __launch_bounds__(256) k_uv(
    const float* __restrict__ X, const unsigned char* __restrict__ Wf,
    const float* __restrict__ bc,
    float* __restrict__ U, float* __restrict__ V, float* __restrict__ SQ,
    unsigned char* __restrict__ XB) {
  __shared__ __align__(16) unsigned char sConv[64*256];
  __shared__ __align__(16) unsigned char sWf[128*256];
  __shared__ float sbc[64];
  int t = threadIdx.x;
  const int lane = t & 63, wave = t >> 6;
  const int g4 = lane >> 4, a15 = lane & 15;
  int b = blockIdx.x;
  int graph = (b & 7) + 8*(b >> 7);
  int nig0 = ((b >> 3) & 15) * 64;
  int base = graph*1024 + nig0;

  if (t < 64) sbc[t] = bc[t];

#pragma unroll
  for (int i = 0; i < 8; ++i) {
    int I = wave*8 + i;
    gl_lds16(Wf + (size_t)I*1024 + lane*16, (void*)(sWf + I*1024));
  }

  {
    int ln = t >> 2, q2 = t & 3;
    int ks = q2 >> 1, oh = (q2 & 1) * 2;
    const float* src = X + (size_t)(base + ln)*64 + ks*32 + oh*8;
    unsigned hu[8], lu[8];
    float sq = 0.f;
#pragma unroll
    for (int q = 0; q < 4; ++q) {
      float4 f = *reinterpret_cast<const float4*>(src + q*4);
      sq += f.x*f.x + f.y*f.y + f.z*f.z + f.w*f.w;
      unsigned short h0 = f2bf(f.x), h1 = f2bf(f.y), h2 = f2bf(f.z), h3 = f2bf(f.w);
      unsigned short l0 = f2bf(f.x - bf2f(h0)), l1 = f2bf(f.y - bf2f(h1));
      unsigned short l2 = f2bf(f.z - bf2f(h2)), l3 = f2bf(f.w - bf2f(h3));
      hu[q*2]   = (unsigned)h0 | ((unsigned)h1 << 16);
      hu[q*2+1] = (unsigned)h2 | ((unsigned)h3 << 16);
      lu[q*2]   = (unsigned)l0 | ((unsigned)l1 << 16);
      lu[q*2+1] = (unsigned)l2 | ((unsigned)l3 << 16);
    }
    sq += __shfl_xor(sq, 1);
    sq += __shfl_xor(sq, 2);
    if (q2 == 0) SQ[base + ln] = sq;
    unsigned char* gdst = XB + (((size_t)graph*2 + ks)*1024 + nig0 + ln)*128 + oh*16;
#pragma unroll
    for (int o = 0; o < 2; ++o) {
      int4 hp = make_int4(hu[o*4], hu[o*4+1], hu[o*4+2], hu[o*4+3]);
      int4 lp = make_int4(lu[o*4], lu[o*4+1], lu[o*4+2], lu[o*4+3]);
      *reinterpret_cast<int4*>(sConv + conv_off(ln, ks*8 + oh + o))     = hp;
      *reinterpret_cast<int4*>(sConv + conv_off(ln, ks*8 + 4 + oh + o)) = lp;
      *reinterpret_cast<int4*>(gdst + o*16)      = hp;
      *reinterpret_cast<int4*>(gdst + 64 + o*16) = lp;
    }
  }
  __syncthreads();

  f32x4 acc[8];
#pragma unroll
  for (int n = 0; n < 8; ++n) acc[n] = f32x4{0.f, 0.f, 0.f, 0.f};
#pragma unroll
  for (int ks = 0; ks < 2; ++ks) {
    int node = wave*16 + a15;
    short8 ah = *reinterpret_cast<const short8*>(sConv + conv_off(node, ks*8 + g4));
    short8 al = *reinterpret_cast<const short8*>(sConv + conv_off(node, ks*8 + 4 + g4));
#pragma unroll
    for (int nt = 0; nt < 8; ++nt) {
      int fb = ((ks*4 + g4)*8 + nt)*2;
      short8 bh = *reinterpret_cast<const short8*>(sWf + fb*256 + a15*16);
      short8 bl = *reinterpret_cast<const short8*>(sWf + (fb+1)*256 + a15*16);
      acc[nt] = __builtin_amdgcn_mfma_f32_16x16x32_bf16(ah, bh, acc[nt], 0, 0, 0);
      acc[nt] = __builtin_amdgcn_mfma_f32_16x16x32_bf16(ah, bl, acc[nt], 0, 0, 0);
      acc[nt] = __builtin_amdgcn_mfma_f32_16x16x32_bf16(al, bh, acc[nt], 0, 0, 0);
      acc[nt] = __builtin_amdgcn_mfma_f32_16x16x32_bf16(al, bl, acc[nt], 0, 0, 0);
    }
  }

#pragma unroll
  for (int nt = 0; nt < 4; ++nt) {
    float bcv = sbc[nt*16 + a15];
#pragma unroll
    for (int i = 0; i < 4; ++i) {
      size_t row = base + wave*16 + g4*4 + i;
      float p = acc[nt][i], q = acc[nt+4][i];
      U[row*64 + nt*16 + a15] = p - q + bcv;
      V[row*64 + nt*16 + a15] = q;
    }
  }
}

// read-side LDS addressing for staged columns
__device__ __forceinline__ int col_byte(int node, int granule) {
  return node*128 + ((granule ^ (node & 7)) << 4);
}

// ------- knn + fused aggregate. 1024 thr / 16 waves / 64 rows per block.
// MODE 0: plain (aggregate -> F).  MODE 1: last (fused output MLP).
// MODE 2: fused next-layer k_uv tail.
// r18 trims (both EXACTNESS-PRESERVING, same IDX set):
//  - phase 3 bisects hi-16 bits only; thr = pp|0xFFFF >= exact u_(24) still
//    yields >=24 candidates and a superset of the exact top-24.
//  - phase 5 skips the tie-col bisect when popc(tie)==need for all rows
//    (generic no-duplicate case): all tied lanes are winners.
template<int MODE>
__global__ void __launch_bounds__(1024) k_knn(
    const unsigned char* __restrict__ XB, const float* __restrict__ SQ,
    const float* __restrict__ U, const float* __restrict__ V,
    float* __restrict__ F,
    const float* __restrict__ Wo1, const float* __restrict__ bo1,
    const float* __restrict__ Wo2, const float* __restrict__ bo2,
    const float* __restrict__ Wo3, const float* __restrict__ bo3,
    const int* __restrict__ batch, float* __restrict__ out, int out_size,
    const unsigned char* __restrict__ WfN, const float* __restrict__ bcN,
    float* __restrict__ Un, float* __restrict__ Vn, float* __restrict__ SQn,
    unsigned char* __restrict__ XBn) {
  __shared__ __align__(16) unsigned char sBuf[49152];
  __shared__ __align__(16) unsigned char sRowB[64*272];
  __shared__ float sCsq[1024];
  __shared__ int nIdx[64*KK];

  int b = blockIdx.x;
  int g = (b & 7) + 8*(b >> 7);          // graph -> XCD g%8 (512 blocks)
  int rowBase = ((b >> 3) & 15) * 64;
  int gbase = g * NPG;
  int t = threadIdx.x;
  const int lane = t & 63, w = t >> 6;
  const int g4 = lane >> 4, a15 = lane & 15;
  const int rg = w >> 2, wc = w & 3;

  // ---- stage 64 row fragments + column squared norms ----
  {
    int row = t >> 4, part = t & 15;
    int ks = part >> 3, o = part & 7;
    const unsigned char* src =
        XB + (((size_t)g*2 + ks)*1024 + rowBase + row)*128 + o*16;
    *reinterpret_cast<int4*>(sRowB + row*272 + part*16) =
        *reinterpret_cast<const int4*>(src);
    if (t < 256) {
      float4 q = *reinterpret_cast<const float4*>(SQ + gbase + t*4);
      *reinterpret_cast<float4*>(sCsq + t*4) = q;
    }
  }
  // prologue: stage chunks 0,1 into bufs 0,1
  {
    int n = t >> 3, gq = t & 7;
    int srcChunk = (n << 3) + (gq ^ (n & 7));
    const unsigned char* sl0 = XB + (((size_t)g*2 + 0)*1024)*128;
    gl_lds16(sl0 + (size_t)srcChunk*16, (void*)(sBuf + 0*16384 + w*1024));
    const unsigned char* sl1 = XB + (((size_t)g*2 + 1)*1024)*128;
    gl_lds16(sl1 + (size_t)srcChunk*16, (void*)(sBuf + 1*16384 + w*1024));
  }
  __syncthreads();

  short8 ahf[2], alf[2];
#pragma unroll
  for (int ks = 0; ks < 2; ++ks) {
    ahf[ks] = *reinterpret_cast<const short8*>(
        sRowB + (rg*16 + a15)*272 + ks*128 + (g4 << 4));
    alf[ks] = *reinterpret_cast<const short8*>(
        sRowB + (rg*16 + a15)*272 + ks*128 + 64 + (g4 << 4));
  }

  f32x4 acc[16];
#pragma unroll
  for (int i = 0; i < 16; ++i) acc[i] = f32x4{0.f, 0.f, 0.f, 0.f};

  // ---- Gram over 16 chunks, 2-deep prefetch, counted vmcnt ----
#pragma unroll
  for (int c = 0; c < 16; ++c) {
    if (c) {
      if (c < 15) asm volatile("s_waitcnt vmcnt(1)" ::: "memory");
      else        asm volatile("s_waitcnt vmcnt(0)" ::: "memory");
      __builtin_amdgcn_sched_barrier(0);
      __builtin_amdgcn_s_barrier();
    }
    if (c < 14) {
      int cn = c + 2;
      const unsigned char* sl =
          XB + (((size_t)g*2 + (cn & 1))*1024 + (cn >> 1)*128)*128;
      int n = t >> 3, gq = t & 7;
      int srcChunk = (n << 3) + (gq ^ (n & 7));
      gl_lds16(sl + (size_t)srcChunk*16, (void*)(sBuf + (cn % 3)*16384 + w*1024));
    }
    const unsigned char* bufc = sBuf + (c % 3)*16384;
    short8 ah = ahf[c & 1], al = alf[c & 1];
#pragma unroll
    for (int tt = 0; tt < 2; ++tt) {
      int node = wc*32 + tt*16 + a15;
      short8 bh = *reinterpret_cast<const short8*>(bufc + col_byte(node, g4));
      short8 bl = *reinterpret_cast<const short8*>(bufc + col_byte(node, 4 + g4));
      int ai = (c >> 1)*2 + tt;
      acc[ai] = __builtin_amdgcn_mfma_f32_16x16x32_bf16(ah, bh, acc[ai], 0, 0, 0);
      acc[ai] = __builtin_amdgcn_mfma_f32_16x16x32_bf16(ah, bl, acc[ai], 0, 0, 0);
      acc[ai] = __builtin_amdgcn_mfma_f32_16x16x32_bf16(al, bh, acc[ai], 0, 0, 0);
      acc[ai] = __builtin_amdgcn_mfma_f32_16x16x32_bf16(al, bl, acc[ai], 0, 0, 0);
    }
  }

  // ---- transpose acc -> per-wave selection regs (r12 geometry) ----
  float v[4][16];
  float* dL = (float*)sBuf;
#pragma unroll
  for (int e = 0; e < 8; ++e) {
    __syncthreads();
#pragma unroll
    for (int k2 = 0; k2 < 2; ++k2) {
      int ai = e*2 + k2;
      int lc = wc*32 + k2*16 + a15;
      float cs = sCsq[e*128 + lc];
#pragma unroll
      for (int i = 0; i < 4; ++i) {
        int r64 = rg*16 + g4*4 + i;
        dL[r64*128 + (lc ^ (((r64 >> 2) & 3) << 3))] = cs - 2.0f*acc[ai][i];
      }
    }
    __syncthreads();
#pragma unroll
    for (int m2 = 0; m2 < 2; ++m2)
#pragma unroll
      for (int r = 0; r < 4; ++r) {
        int rr = w*4 + r;
        v[r][e*2 + m2] = dL[rr*128 + ((m2*64 + lane) ^ (((rr >> 2) & 3) << 3))];
      }
  }
  __syncthreads();

  unsigned long long* sCmp = (unsigned long long*)sBuf;
  const unsigned long long mlt = (1ull << lane) - 1ull;

  // phase 2: per-lane min per row (value only), in ord space
  unsigned uu[4];
#pragma unroll
  for (int r = 0; r < 4; ++r) {
    float bm = v[r][0];
#pragma unroll
    for (int m = 1; m < 16; ++m) bm = fminf(bm, v[r][m]);
    uu[r] = ordf(bm);
  }

  // phase 3 (r18): hi-16 radix bisection -> pp = u_(24) & 0xFFFF0000; thr = pp|0xFFFF
  unsigned pp[4] = {0u, 0u, 0u, 0u};
#pragma unroll
  for (int bb = 31; bb >= 16; --bb) {
#pragma unroll
    for (int r = 0; r < 4; ++r) {
      unsigned q = pp[r] | (1u << bb);
      if ((int)__popcll(__ballot(uu[r] < q)) < KK) pp[r] = q;
    }
  }
#pragma unroll
  for (int r = 0; r < 4; ++r) pp[r] |= 0xFFFFu;

  // phase 4: flag (ord <= thr), ballot-compact to sCmp (order-free slots)
  int total[4];
#pragma unroll
  for (int r = 0; r < 4; ++r) {
    int base = 0;
#pragma unroll
    for (int m = 0; m < 16; ++m) {
      unsigned ov = ordf(v[r][m]);
      bool f = ov <= pp[r];
      unsigned long long bal = __ballot(f);
      int slot = base + (int)__popcll(bal & mlt);
      if (f && slot < 64)
        sCmp[(w*4 + r)*64 + slot] =
            ((unsigned long long)ov << 32) | (unsigned)(lane + (m << 6));
      base += (int)__popcll(bal);
    }
    total[r] = base;
  }

  unsigned cu2[4]; int col2[4];
#pragma unroll
  for (int r = 0; r < 4; ++r) {
    unsigned long long kp = (lane < total[r]) ? sCmp[(w*4 + r)*64 + lane] : ~0ull;
    cu2[r] = (unsigned)(kp >> 32);
    col2[r] = (int)(unsigned)(kp & 0xFFFFFFFFull);
  }

  if (MODE == 2) {
    // sCmp consumed; stage next-layer W fragments (32 KB) into sBuf[0..32768)
    __syncthreads();
#pragma unroll
    for (int i = 0; i < 2; ++i) {
      int I = w*2 + i;
      gl_lds16(WfN + (size_t)I*1024 + lane*16, (void*)(sBuf + I*1024));
    }
  }

  // phase 5: exact value bisection on candidates (full 32 bits — required)
  unsigned p2[4] = {0u, 0u, 0u, 0u};
#pragma unroll
  for (int bb = 31; bb >= 0; --bb) {
#pragma unroll
    for (int r = 0; r < 4; ++r) {
      unsigned q = p2[r] | (1u << bb);
      if ((int)__popcll(__ballot(cu2[r] < q)) < KK) p2[r] = q;
    }
  }
  int need[4]; bool tie[4]; int cntT[4];
#pragma unroll
  for (int r = 0; r < 4; ++r) {
    need[r] = KK - (int)__popcll(__ballot(cu2[r] < p2[r]));
    tie[r] = (cu2[r] == p2[r]);
    cntT[r] = (int)__popcll(__ballot(tie[r]));
  }
  // r18 tie shortcut: generic case (no duplicate 24th value) takes all tied lanes
  unsigned p3[4];
  bool allexact = cntT[0] == need[0] && cntT[1] == need[1] &&
                  cntT[2] == need[2] && cntT[3] == need[3];
  if (allexact) {
#pragma unroll
    for (int r = 0; r < 4; ++r) p3[r] = 0xFFFFFFFFu;
  } else {
#pragma unroll
    for (int r = 0; r < 4; ++r) p3[r] = 0u;
#pragma unroll
    for (int bb = 9; bb >= 0; --bb) {
#pragma unroll
      for (int r = 0; r < 4; ++r) {
        unsigned q = p3[r] | (1u << bb);
        if ((int)__popcll(__ballot(tie[r] && ((unsigned)col2[r] < q))) < need[r]) p3[r] = q;
      }
    }
  }

  bool allfast = total[0] <= 64 && total[1] <= 64 && total[2] <= 64 && total[3] <= 64;
  if (allfast) {
#pragma unroll
    for (int r = 0; r < 4; ++r) {
      bool in24 = (cu2[r] < p2[r]) || (tie[r] && ((unsigned)col2[r] <= p3[r]));
      unsigned long long ball = __ballot(in24);
      int pos = (int)__popcll(ball & mlt);
      if (in24) nIdx[(w*4 + r)*KK + pos] = col2[r];
    }
  } else {
#pragma unroll
    for (int r = 0; r < 4; ++r) {
      unsigned selm = 0;
      for (int it = 0; it < KK; ++it) {
        float bv = FLTMAX; int bj = 0x7fffffff;
#pragma unroll
        for (int m = 0; m < 16; ++m) {
          float vv = ((selm >> m) & 1) ? FLTMAX : v[r][m];
          int col = lane + (m << 6);
          bool bsel = vv < bv; bv = bsel ? vv : bv; bj = bsel ? col : bj;
        }
#pragma unroll
        for (int s = 32; s; s >>= 1) {
          float ov = __shfl_xor(bv, s); int oj = __shfl_xor(bj, s);
          bool bsel = (ov < bv) || (ov == bv && oj < bj);
          bv = bsel ? ov : bv; bj = bsel ? oj : bj;
        }
        if (lane == (bj & 63)) selm |= 1u << (bj >> 6);
        if (lane == 0) nIdx[(w*4 + r)*KK + it] = bj;
      }
    }
  }

  // ---- fused aggregate ----
  if (MODE == 0) {
#pragma unroll
    for (int r = 0; r < 4; ++r) {
      int row = rowBase + w*4 + r;
      float mx = -FLTMAX;
#pragma unroll
      for (int tt = 0; tt < KK; ++tt) {
        int j = nIdx[(w*4 + r)*KK + tt];
        mx = fmaxf(mx, V[((size_t)(gbase + j))*64 + lane]);
      }
      size_t off = (size_t)(gbase + row)*64 + lane;
      F[off] += elu1(U[off] + mx);
    }
  } else if (MODE == 1) {
    float* sOutF = (float*)sRowB;              // [64][68]
#pragma unroll
    for (int r = 0; r < 4; ++r) {
      int row = rowBase + w*4 + r;
      float mx = -FLTMAX;
#pragma unroll
      for (int tt = 0; tt < KK; ++tt) {
        int j = nIdx[(w*4 + r)*KK + tt];
        mx = fmaxf(mx, V[((size_t)(gbase + j))*64 + lane]);
      }
      size_t off = (size_t)(gbase + row)*64 + lane;
      sOutF[(w*4 + r)*68 + lane] = F[off] + elu1(U[off] + mx);
    }
    __syncthreads();

    float* sW1o = (float*)sBuf;
    float* sW2o = sW1o + 64*64;
    float* sW3o = sW2o + 64*32;
    float* sB1o = sW3o + 32*8;
    float* sB2o = sB1o + 64;
    float* sB3o = sB2o + 32;
    float* sO1  = sB3o + 8;
    for (int i = t; i < 64*64; i += 1024) sW1o[i] = Wo1[i];
    for (int i = t; i < 64*32; i += 1024) sW2o[i] = Wo2[i];
    if (t < 256) sW3o[t] = Wo3[t];
    if (t < 64) sB1o[t] = bo1[t];
    if (t < 32) sB2o[t] = bo2[t];
    if (t < 8)  sB3o[t] = bo3[t];
    __syncthreads();

    int ln = t >> 3, qd = t & 7;
    if (t < 512) {
      float a1[8];
#pragma unroll
      for (int dd = 0; dd < 8; ++dd) a1[dd] = sB1o[qd*8 + dd];
#pragma unroll 4
      for (int k = 0; k < 64; ++k) {
        float fk = sOutF[ln*68 + k];
#pragma unroll
        for (int dd = 0; dd < 8; ++dd) a1[dd] += fk*sW1o[k*64 + qd*8 + dd];
      }
#pragma unroll
      for (int dd = 0; dd < 8; ++dd) sO1[ln*65 + qd*8 + dd] = elu1(a1[dd]);
    }
    __syncthreads();

    float* sO2 = (float*)sRowB;
    if (t < 512) {
      float a2[4];
#pragma unroll
      for (int dd = 0; dd < 4; ++dd) a2[dd] = sB2o[qd*4 + dd];
#pragma unroll 4
      for (int k = 0; k < 64; ++k) {
        float ok = sO1[ln*65 + k];
#pragma unroll
        for (int dd = 0; dd < 4; ++dd) a2[dd] += ok*sW2o[k*32 + qd*4 + dd];
      }
#pragma unroll
      for (int dd = 0; dd < 4; ++dd) sO2[ln*34 + qd*4 + dd] = elu1(a2[dd]);
    }
    __syncthreads();

    if (t < 512) {
      int nodeG = gbase + rowBase + ln;
      float a3 = sB3o[qd];
#pragma unroll
      for (int k = 0; k < 32; ++k) a3 += sO2[ln*34 + k]*sW3o[k*8 + qd];
      out[(size_t)nodeG*8 + qd] = a3;
      if (qd == 0 && out_size >= NN*9) out[(size_t)NN*8 + nodeG] = (float)batch[nodeG];
    }
  } else {
    // MODE 2: aggregate -> F global + LDS, then fused next-layer k_uv tail
    float* sOutF = (float*)sRowB;              // [64][68]
#pragma unroll
    for (int r = 0; r < 4; ++r) {
      int row = rowBase + w*4 + r;
      float mx = -FLTMAX;
#pragma unroll
      for (int tt = 0; tt < KK; ++tt) {
        int j = nIdx[(w*4 + r)*KK + tt];
        mx = fmaxf(mx, V[((size_t)(gbase + j))*64 + lane]);
      }
      size_t off = (size_t)(gbase + row)*64 + lane;
      float nf = F[off] + elu1(U[off] + mx);
      F[off] = nf;
      sOutF[(w*4 + r)*68 + lane] = nf;
    }
    asm volatile("s_waitcnt vmcnt(0)" ::: "memory");   // WfN staging done
    __builtin_amdgcn_sched_barrier(0);
    __syncthreads();

    unsigned char* sConvT = sBuf + 32768;
    if (t < 256) {
      int ln = t >> 2, q2 = t & 3;
      int ks = q2 >> 1, oh = (q2 & 1) * 2;
      const float* src = sOutF + ln*68 + ks*32 + oh*8;
      unsigned hu[8], lu[8];
      float sq = 0.f;
#pragma unroll
      for (int q = 0; q < 4; ++q) {
        float4 f = *reinterpret_cast<const float4*>(src + q*4);
        sq += f.x*f.x + f.y*f.y + f.z*f.z + f.w*f.w;
        unsigned short h0 = f2bf(f.x), h1 = f2bf(f.y), h2 = f2bf(f.z), h3 = f2bf(f.w);
        unsigned short l0 = f2bf(f.x - bf2f(h0)), l1 = f2bf(f.y - bf2f(h1));
        unsigned short l2 = f2bf(f.z - bf2f(h2)), l3 = f2bf(f.w - bf2f(h3));
        hu[q*2]   = (unsigned)h0 | ((unsigned)h1 << 16);
        hu[q*2+1] = (unsigned)h2 | ((unsigned)h3 << 16);
        lu[q*2]   = (unsigned)l0 | ((unsigned)l1 << 16);
        lu[q*2+1] = (unsigned)l2 | ((unsigned)l3 << 16);
      }
      sq += __shfl_xor(sq, 1);
      sq += __shfl_xor(sq, 2);
      if (q2 == 0) SQn[gbase + rowBase + ln] = sq;
      unsigned char* gdst = XBn + (((size_t)g*2 + ks)*1024 + rowBase + ln)*128 + oh*16;
#pragma unroll
      for (int o = 0; o < 2; ++o) {
        int4 hp = make_int4(hu[o*4], hu[o*4+1], hu[o*4+2], hu[o*4+3]);
        int4 lp = make_int4(lu[o*4], lu[o*4+1], lu[o*4+2], lu[o*4+3]);
        *reinterpret_cast<int4*>(sConvT + conv_off(ln, ks*8 + oh + o))     = hp;
        *reinterpret_cast<int4*>(sConvT + conv_off(ln, ks*8 + 4 + oh + o)) = lp;
        *reinterpret_cast<int4*>(gdst + o*16)      = hp;
        *reinterpret_cast<int4*>(gdst + 64 + o*16) = lp;
      }
    }
    __syncthreads();

    f32x4 acc2[2];
    acc2[0] = f32x4{0.f, 0.f, 0.f, 0.f};
    acc2[1] = f32x4{0.f, 0.f, 0.f, 0.f};
    int nodeT = (w & 3)*16 + a15;
    int ntp = w >> 2;
#pragma unroll
    for (int ks2 = 0; ks2 < 2; ++ks2) {
      short8 ah2 = *reinterpret_cast<const short8*>(sConvT + conv_off(nodeT, ks2*8 + g4));
      short8 al2 = *reinterpret_cast<const short8*>(sConvT + conv_off(nodeT, ks2*8 + 4 + g4));
#pragma unroll
      for (int q = 0; q < 2; ++q) {
        int nt = ntp + q*4;
        int fb = ((ks2*4 + g4)*8 + nt)*2;
        short8 bh = *reinterpret_cast<const short8*>(sBuf + fb*256 + a15*16);
        short8 bl = *reinterpret_cast<const short8*>(sBuf + (fb+1)*256 + a15*16);
        acc2[q] = __builtin_amdgcn_mfma_f32_16x16x32_bf16(ah2, bh, acc2[q], 0, 0, 0);
        acc2[q] = __builtin_amdgcn_mfma_f32_16x16x32_bf16(ah2, bl, acc2[q], 0, 0, 0);
        acc2[q] = __builtin_amdgcn_mfma_f32_16x16x32_bf16(al2, bh, acc2[q], 0, 0, 0);
        acc2[q] = __builtin_amdgcn_mfma_f32_16x16x32_bf16(al2, bl, acc2[q], 0, 0, 0);
      }
    }
    float bcv = bcN[ntp*16 + a15];
#pragma unroll
    for (int i = 0; i < 4; ++i) {
      size_t row = (size_t)gbase + rowBase + (w & 3)*16 + g4*4 + i;
      float p = acc2[0][i], q = acc2[1][i];
      Un[row*64 + ntp*16 + a15] = p - q + bcv;
      Vn[row*64 + ntp*16 + a15] = q;
    }
  }
}

extern "C" void kernel_launch(void* const* d_in, const int* in_sizes, int n_in,
                              void* d_out, int out_size, void* d_ws, size_t ws_size,
                              hipStream_t stream) {
  const float* x     = (const float*)d_in[0];
  const int*   batch = (const int*)d_in[1];
  const float* W1 = (const float*)d_in[2];
  const float* b1 = (const float*)d_in[3];
  const float* W2 = (const float*)d_in[4];
  const float* b2 = (const float*)d_in[5];
  const float* Wc[3] = {(const float*)d_in[6], (const float*)d_in[8], (const float*)d_in[10]};
  const float* bc[3] = {(const float*)d_in[7], (const float*)d_in[9], (const float*)d_in[11]};
  const float* Wo1 = (const float*)d_in[12];
  const float* bo1 = (const float*)d_in[13];
  const float* Wo2 = (const float*)d_in[14];
  const float* bo2 = (const float*)d_in[15];
  const float* Wo3 = (const float*)d_in[16];
  const float* bo3 = (const float*)d_in[17];

  float* outF = (float*)d_out;
  const size_t NEED = (size_t)(5*NN*64 + 2*NN)*4 + (size_t)2*NN*256 + 98304;

  if (ws_size >= NEED) {
    float* ws = (float*)d_ws;
    float* F0  = ws;
    float* U0  = F0 + (size_t)NN*64;
    float* V0  = U0 + (size_t)NN*64;
    float* U1  = V0 + (size_t)NN*64;
    float* V1  = U1 + (size_t)NN*64;
    float* SQ0 = V1 + (size_t)NN*64;
    float* SQ1 = SQ0 + NN;
    unsigned char* XB0 = (unsigned char*)(SQ1 + NN);
    unsigned char* XB1 = XB0 + (size_t)NN*256;
    unsigned char* WfG = XB1 + (size_t)NN*256;

    k_mlp_in<<<NN/128 + 3, 256, 0, stream>>>(x, W1, b1, W2, b2, F0,
                                             Wc[0], Wc[1], Wc[2], WfG);
    k_uv<<<NN/64, 256, 0, stream>>>(F0, WfG, bc[0], U0, V0, SQ0, XB0);
    k_knn<2><<<BG*(NPG/64), 1024, 0, stream>>>(XB0, SQ0, U0, V0, F0,
        Wo1, bo1, Wo2, bo2, Wo3, bo3, batch, outF, out_size,
        WfG + 32768, bc[1], U1, V1, SQ1, XB1);
    k_knn<2><<<BG*(NPG/64), 1024, 0, stream>>>(XB1, SQ1, U1, V1, F0,
        Wo1, bo1, Wo2, bo2, Wo3, bo3, batch, outF, out_size,
        WfG + 65536, bc[2], U0, V0, SQ0, XB0);
    k_knn<1><<<BG*(NPG/64), 1024, 0, stream>>>(XB0, SQ0, U0, V0, F0,
        Wo1, bo1, Wo2, bo2, Wo3, bo3, batch, outF, out_size,
        (const unsigned char*)0, (const float*)0,
        (float*)0, (float*)0, (float*)0, (unsigned char*)0);
  } else {
    float* ws = (float*)d_ws;
    float* F0 = ws;
    float* U  = ws + (size_t)NN*64;
    float* V  = ws + (size_t)2*NN*64;
    float* SQ = ws + (size_t)3*NN*64;
    unsigned char* XB = (unsigned char*)(SQ + NN);
    unsigned char* WfG = XB + (size_t)NN*256;

    k_mlp_in<<<NN/128 + 3, 256, 0, stream>>>(x, W1, b1, W2, b2, F0,
                                             Wc[0], Wc[1], Wc[2], WfG);
    for (int l = 0; l < 3; ++l) {
      k_uv<<<NN/64, 256, 0, stream>>>(F0, WfG + (size_t)l*32768, bc[l], U, V, SQ, XB);
      if (l < 2)
        k_knn<0><<<BG*(NPG/64), 1024, 0, stream>>>(XB, SQ, U, V, F0,
            Wo1, bo1, Wo2, bo2, Wo3, bo3, batch, outF, out_size,
            (const unsigned char*)0, (const float*)0,
            (float*)0, (float*)0, (float*)0, (unsigned char*)0);
      else
        k_knn<1><<<BG*(NPG/64), 1024, 0, stream>>>(XB, SQ, U, V, F0,
            Wo1, bo1, Wo2, bo2, Wo3, bo3, batch, outF, out_size,
            (const unsigned char*)0, (const float*)0,
            (float*)0, (float*)0, (float*)0, (unsigned char*)0);
    }
  }
}

// Round 19
// 227.803 us; speedup vs baseline: 1.7528x; 1.0031x over previous
//
#include <hip/hip_runtime.h>
#include <hip/hip_bf16.h>
#include <math.h>

#define NN   32768
#define BG   32
#define NPG  1024
#define HD   64
#define KK   24          // neighbors

#define FLTMAX 3.402823466e38f

typedef __attribute__((ext_vector_type(8))) short short8;
typedef __attribute__((ext_vector_type(4))) float f32x4;

__device__ __forceinline__ float elu1(float x) { return x > 0.f ? x : expm1f(x); }

__device__ __forceinline__ unsigned short f2bf(float x) {  // RNE to bf16
  unsigned u = __float_as_uint(x);
  unsigned r = (u + 0x7FFFu + ((u >> 16) & 1u)) >> 16;
  return (unsigned short)r;
}
__device__ __forceinline__ float bf2f(unsigned short h) {
  return __uint_as_float(((unsigned)h) << 16);
}
// monotone float -> uint order transform (finite values)
__device__ __forceinline__ unsigned ordf(float f) {
  unsigned b = __float_as_uint(f);
  return (b & 0x80000000u) ? ~b : (b | 0x80000000u);
}

// async global->LDS, 16B per lane; lds base must be wave-uniform (HW adds lane*16)
__device__ __forceinline__ void gl_lds16(const void* g, void* lds) {
  __builtin_amdgcn_global_load_lds(
      (const __attribute__((address_space(1))) unsigned int*)g,
      (__attribute__((address_space(3))) unsigned int*)lds, 16, 0, 0);
}

// ---------------- input MLP (+ folded-in Wc fragment conversion blocks) ----------------
__global__ void __launch_bounds__(256) k_mlp_in(
    const float* __restrict__ x, const float* __restrict__ W1, const float* __restrict__ b1,
    const float* __restrict__ W2, const float* __restrict__ b2, float* __restrict__ F,
    const float* __restrict__ Wc0, const float* __restrict__ Wc1,
    const float* __restrict__ Wc2, unsigned char* __restrict__ Wf) {
  __shared__ float sW1[8*64];
  __shared__ float sW2[64*64];
  __shared__ float sb1[64];
  __shared__ float sb2[64];
  int t = threadIdx.x;
  if (blockIdx.x >= NN/128) {
    int lb = blockIdx.x - NN/128;
    const float* Wc = lb == 0 ? Wc0 : (lb == 1 ? Wc1 : Wc2);
    unsigned char* dst = Wf + (size_t)lb*32768;
    int f = t >> 1, colHalf = t & 1;
    int part = f & 1, nt = (f >> 1) & 7, oct = (f >> 4) & 3, ks = f >> 6;
#pragma unroll
    for (int cc = 0; cc < 8; ++cc) {
      int c8 = colHalf*8 + cc;
      int dp = nt*16 + c8;
      const float* wsrc = (dp < 64) ? (Wc + dp) : (Wc + 64*64 + (dp - 64));
      unsigned short sh[8];
#pragma unroll
      for (int j = 0; j < 8; ++j) {
        float w = wsrc[(ks*32 + oct*8 + j)*64];
        unsigned short hi = f2bf(w);
        sh[j] = part ? f2bf(w - bf2f(hi)) : hi;
      }
      *reinterpret_cast<int4*>(dst + f*256 + c8*16) = make_int4(
          (unsigned)sh[0] | ((unsigned)sh[1] << 16), (unsigned)sh[2] | ((unsigned)sh[3] << 16),
          (unsigned)sh[4] | ((unsigned)sh[5] << 16), (unsigned)sh[6] | ((unsigned)sh[7] << 16));
    }
    return;
  }
  for (int i = t; i < 8*64; i += 256) sW1[i] = W1[i];
  for (int i = t; i < 64*64; i += 256) sW2[i] = W2[i];
  if (t < 64) { sb1[t] = b1[t]; sb2[t] = b2[t]; }
  __syncthreads();
  int node = blockIdx.x*128 + (t & 127);
  int half = t >> 7;
  float xr[8];
#pragma unroll
  for (int i = 0; i < 8; ++i) xr[i] = x[node*8 + i];
  float h1[64];
#pragma unroll 8
  for (int k = 0; k < 64; ++k) {
    float a = sb1[k];
#pragma unroll
    for (int i = 0; i < 8; ++i) a += xr[i]*sW1[i*64+k];
    h1[k] = elu1(a);
  }
#pragma unroll 2
  for (int dd = 0; dd < 32; ++dd) {
    int d = half*32 + dd;
    float a = sb2[d];
#pragma unroll
    for (int k = 0; k < 64; ++k) a += h1[k]*sW2[k*64+d];
    F[node*64 + d] = elu1(a);
  }
}

// split-bf16 conv-buffer addressing
__device__ __forceinline__ int conv_off(int node, int g) {
  return node*256 + ((((g & 7) ^ (node & 7)) | (g & 8)) << 4);
}

// ---- per-layer (MFMA): U = X@(A-B)+bc, V = X@B (fp32), SQ, XB = split-bf16(X) ----
// (UNCHANGED from r13..r18 — passed at absmax 0.265625.)
__global__ void __launch_bounds__(256) k_uv(
    const float* __restrict__ X, const unsigned char* __restrict__ Wf,
    const float* __restrict__ bc,
    float* __restrict__ U, float* __restrict__ V, float* __restrict__ SQ,
    unsigned char* __restrict__ XB) {
  __shared__ __align__(16) unsigned char sConv[64*256];
  __shared__ __align__(16) unsigned char sWf[128*256];
  __shared__ float sbc[64];
  int t = threadIdx.x;
  const int lane = t & 63, wave = t >> 6;
  const int g4 = lane >> 4, a15 = lane & 15;
  int b = blockIdx.x;
  int graph = (b & 7) + 8*(b >> 7);
  int nig0 = ((b >> 3) & 15) * 64;
  int base = graph*1024 + nig0;

  if (t < 64) sbc[t] = bc[t];

#pragma unroll
  for (int i = 0; i < 8; ++i) {
    int I = wave*8 + i;
    gl_lds16(Wf + (size_t)I*1024 + lane*16, (void*)(sWf + I*1024));
  }

  {
    int ln = t >> 2, q2 = t & 3;
    int ks = q2 >> 1, oh = (q2 & 1) * 2;
    const float* src = X + (size_t)(base + ln)*64 + ks*32 + oh*8;
    unsigned hu[8], lu[8];
    float sq = 0.f;
#pragma unroll
    for (int q = 0; q < 4; ++q) {
      float4 f = *reinterpret_cast<const float4*>(src + q*4);
      sq += f.x*f.x + f.y*f.y + f.z*f.z + f.w*f.w;
      unsigned short h0 = f2bf(f.x), h1 = f2bf(f.y), h2 = f2bf(f.z), h3 = f2bf(f.w);
      unsigned short l0 = f2bf(f.x - bf2f(h0)), l1 = f2bf(f.y - bf2f(h1));
      unsigned short l2 = f2bf(f.z - bf2f(h2)), l3 = f2bf(f.w - bf2f(h3));
      hu[q*2]   = (unsigned)h0 | ((unsigned)h1 << 16);
      hu[q*2+1] = (unsigned)h2 | ((unsigned)h3 << 16);
      lu[q*2]   = (unsigned)l0 | ((unsigned)l1 << 16);
      lu[q*2+1] = (unsigned)l2 | ((unsigned)l3 << 16);
    }
    sq += __shfl_xor(sq, 1);
    sq += __shfl_xor(sq, 2);
    if (q2 == 0) SQ[base + ln] = sq;
    unsigned char* gdst = XB + (((size_t)graph*2 + ks)*1024 + nig0 + ln)*128 + oh*16;
#pragma unroll
    for (int o = 0; o < 2; ++o) {
      int4 hp = make_int4(hu[o*4], hu[o*4+1], hu[o*4+2], hu[o*4+3]);
      int4 lp = make_int4(lu[o*4], lu[o*4+1], lu[o*4+2], lu[o*4+3]);
      *reinterpret_cast<int4*>(sConv + conv_off(ln, ks*8 + oh + o))     = hp;
      *reinterpret_cast<int4*>(sConv + conv_off(ln, ks*8 + 4 + oh + o)) = lp;
      *reinterpret_cast<int4*>(gdst + o*16)      = hp;
      *reinterpret_cast<int4*>(gdst + 64 + o*16) = lp;
    }
  }
  __syncthreads();

  f32x4 acc[8];
#pragma unroll
  for (int n = 0; n < 8; ++n) acc[n] = f32x4{0.f, 0.f, 0.f, 0.f};
#pragma unroll
  for (int ks = 0; ks < 2; ++ks) {
    int node = wave*16 + a15;
    short8 ah = *reinterpret_cast<const short8*>(sConv + conv_off(node, ks*8 + g4));
    short8 al = *reinterpret_cast<const short8*>(sConv + conv_off(node, ks*8 + 4 + g4));
#pragma unroll
    for (int nt = 0; nt < 8; ++nt) {
      int fb = ((ks*4 + g4)*8 + nt)*2;
      short8 bh = *reinterpret_cast<const short8*>(sWf + fb*256 + a15*16);
      short8 bl = *reinterpret_cast<const short8*>(sWf + (fb+1)*256 + a15*16);
      acc[nt] = __builtin_amdgcn_mfma_f32_16x16x32_bf16(ah, bh, acc[nt], 0, 0, 0);
      acc[nt] = __builtin_amdgcn_mfma_f32_16x16x32_bf16(ah, bl, acc[nt], 0, 0, 0);
      acc[nt] = __builtin_amdgcn_mfma_f32_16x16x32_bf16(al, bh, acc[nt], 0, 0, 0);
      acc[nt] = __builtin_amdgcn_mfma_f32_16x16x32_bf16(al, bl, acc[nt], 0, 0, 0);
    }
  }

#pragma unroll
  for (int nt = 0; nt < 4; ++nt) {
    float bcv = sbc[nt*16 + a15];
#pragma unroll
    for (int i = 0; i < 4; ++i) {
      size_t row = base + wave*16 + g4*4 + i;
      float p = acc[nt][i], q = acc[nt+4][i];
      U[row*64 + nt*16 + a15] = p - q + bcv;
      V[row*64 + nt*16 + a15] = q;
    }
  }
}

// read-side LDS addressing for staged columns
__device__ __forceinline__ int col_byte(int node, int granule) {
  return node*128 + ((granule ^ (node & 7)) << 4);
}

// ------- knn + fused aggregate. 1024 thr / 16 waves / 64 rows per block.
// MODE 0: plain.  MODE 1: last (fused output MLP).  MODE 2: fused next-layer k_uv tail.
// r19: lane owns cols C(m) = (m>>1)*128 + lane*2 + (m&1) — the two cols per
// eighth are ADJACENT, so the transpose read is one b64 per row per eighth
// (32 ds_read_b64 vs 64 ds_read_b32). Threshold theorem holds for any lane
// partition; phase 5 and aggregate are set-based -> IDX set & numerics identical.
template<int MODE>
__global__ void __launch_bounds__(1024) k_knn(
    const unsigned char* __restrict__ XB, const float* __restrict__ SQ,
    const float* __restrict__ U, const float* __restrict__ V,
    float* __restrict__ F,
    const float* __restrict__ Wo1, const float* __restrict__ bo1,
    const float* __restrict__ Wo2, const float* __restrict__ bo2,
    const float* __restrict__ Wo3, const float* __restrict__ bo3,
    const int* __restrict__ batch, float* __restrict__ out, int out_size,
    const unsigned char* __restrict__ WfN, const float* __restrict__ bcN,
    float* __restrict__ Un, float* __restrict__ Vn, float* __restrict__ SQn,
    unsigned char* __restrict__ XBn) {
  __shared__ __align__(16) unsigned char sBuf[49152];
  __shared__ __align__(16) unsigned char sRowB[64*272];
  __shared__ float sCsq[1024];
  __shared__ int nIdx[64*KK];

  int b = blockIdx.x;
  int g = (b & 7) + 8*(b >> 7);          // graph -> XCD g%8 (512 blocks)
  int rowBase = ((b >> 3) & 15) * 64;
  int gbase = g * NPG;
  int t = threadIdx.x;
  const int lane = t & 63, w = t >> 6;
  const int g4 = lane >> 4, a15 = lane & 15;
  const int rg = w >> 2, wc = w & 3;

  // ---- stage 64 row fragments + column squared norms ----
  {
    int row = t >> 4, part = t & 15;
    int ks = part >> 3, o = part & 7;
    const unsigned char* src =
        XB + (((size_t)g*2 + ks)*1024 + rowBase + row)*128 + o*16;
    *reinterpret_cast<int4*>(sRowB + row*272 + part*16) =
        *reinterpret_cast<const int4*>(src);
    if (t < 256) {
      float4 q = *reinterpret_cast<const float4*>(SQ + gbase + t*4);
      *reinterpret_cast<float4*>(sCsq + t*4) = q;
    }
  }
  // prologue: stage chunks 0,1 into bufs 0,1
  {
    int n = t >> 3, gq = t & 7;
    int srcChunk = (n << 3) + (gq ^ (n & 7));
    const unsigned char* sl0 = XB + (((size_t)g*2 + 0)*1024)*128;
    gl_lds16(sl0 + (size_t)srcChunk*16, (void*)(sBuf + 0*16384 + w*1024));
    const unsigned char* sl1 = XB + (((size_t)g*2 + 1)*1024)*128;
    gl_lds16(sl1 + (size_t)srcChunk*16, (void*)(sBuf + 1*16384 + w*1024));
  }
  __syncthreads();

  short8 ahf[2], alf[2];
#pragma unroll
  for (int ks = 0; ks < 2; ++ks) {
    ahf[ks] = *reinterpret_cast<const short8*>(
        sRowB + (rg*16 + a15)*272 + ks*128 + (g4 << 4));
    alf[ks] = *reinterpret_cast<const short8*>(
        sRowB + (rg*16 + a15)*272 + ks*128 + 64 + (g4 << 4));
  }

  f32x4 acc[16];
#pragma unroll
  for (int i = 0; i < 16; ++i) acc[i] = f32x4{0.f, 0.f, 0.f, 0.f};

  // ---- Gram over 16 chunks, 2-deep prefetch, counted vmcnt ----
#pragma unroll
  for (int c = 0; c < 16; ++c) {
    if (c) {
      if (c < 15) asm volatile("s_waitcnt vmcnt(1)" ::: "memory");
      else        asm volatile("s_waitcnt vmcnt(0)" ::: "memory");
      __builtin_amdgcn_sched_barrier(0);
      __builtin_amdgcn_s_barrier();
    }
    if (c < 14) {
      int cn = c + 2;
      const unsigned char* sl =
          XB + (((size_t)g*2 + (cn & 1))*1024 + (cn >> 1)*128)*128;
      int n = t >> 3, gq = t & 7;
      int srcChunk = (n << 3) + (gq ^ (n & 7));
      gl_lds16(sl + (size_t)srcChunk*16, (void*)(sBuf + (cn % 3)*16384 + w*1024));
    }
    const unsigned char* bufc = sBuf + (c % 3)*16384;
    short8 ah = ahf[c & 1], al = alf[c & 1];
#pragma unroll
    for (int tt = 0; tt < 2; ++tt) {
      int node = wc*32 + tt*16 + a15;
      short8 bh = *reinterpret_cast<const short8*>(bufc + col_byte(node, g4));
      short8 bl = *reinterpret_cast<const short8*>(bufc + col_byte(node, 4 + g4));
      int ai = (c >> 1)*2 + tt;
      acc[ai] = __builtin_amdgcn_mfma_f32_16x16x32_bf16(ah, bh, acc[ai], 0, 0, 0);
      acc[ai] = __builtin_amdgcn_mfma_f32_16x16x32_bf16(ah, bl, acc[ai], 0, 0, 0);
      acc[ai] = __builtin_amdgcn_mfma_f32_16x16x32_bf16(al, bh, acc[ai], 0, 0, 0);
      acc[ai] = __builtin_amdgcn_mfma_f32_16x16x32_bf16(al, bl, acc[ai], 0, 0, 0);
    }
  }

  // ---- transpose acc -> per-wave selection regs ----
  // Write side unchanged (r12 geometry + row-XOR swizzle). Read side (r19):
  // v[r][2e+j] = col e*128 + lane*2 + j; bit0 survives the XOR -> b64 reads.
  float v[4][16];
  float* dL = (float*)sBuf;
#pragma unroll
  for (int e = 0; e < 8; ++e) {
    __syncthreads();
#pragma unroll
    for (int k2 = 0; k2 < 2; ++k2) {
      int ai = e*2 + k2;
      int lc = wc*32 + k2*16 + a15;
      float cs = sCsq[e*128 + lc];
#pragma unroll
      for (int i = 0; i < 4; ++i) {
        int r64 = rg*16 + g4*4 + i;
        dL[r64*128 + (lc ^ (((r64 >> 2) & 3) << 3))] = cs - 2.0f*acc[ai][i];
      }
    }
    __syncthreads();
#pragma unroll
    for (int r = 0; r < 4; ++r) {
      int rr = w*4 + r;
      float2 rv = *reinterpret_cast<const float2*>(
          dL + rr*128 + ((lane*2) ^ (((rr >> 2) & 3) << 3)));
      v[r][e*2 + 0] = rv.x;
      v[r][e*2 + 1] = rv.y;
    }
  }
  __syncthreads();

  unsigned long long* sCmp = (unsigned long long*)sBuf;
  const unsigned long long mlt = (1ull << lane) - 1ull;

  // phase 2: per-lane min per row (value only), in ord space
  unsigned uu[4];
#pragma unroll
  for (int r = 0; r < 4; ++r) {
    float bm = v[r][0];
#pragma unroll
    for (int m = 1; m < 16; ++m) bm = fminf(bm, v[r][m]);
    uu[r] = ordf(bm);
  }

  // phase 3: hi-16 radix bisection -> thr = pp|0xFFFF (superset guarantee holds
  // for any lane partition: 24 smallest lane-mins are 24 values <= thr)
  unsigned pp[4] = {0u, 0u, 0u, 0u};
#pragma unroll
  for (int bb = 31; bb >= 16; --bb) {
#pragma unroll
    for (int r = 0; r < 4; ++r) {
      unsigned q = pp[r] | (1u << bb);
      if ((int)__popcll(__ballot(uu[r] < q)) < KK) pp[r] = q;
    }
  }
#pragma unroll
  for (int r = 0; r < 4; ++r) pp[r] |= 0xFFFFu;

  // phase 4: flag (ord <= thr), ballot-compact to sCmp (order-free slots)
  int total[4];
#pragma unroll
  for (int r = 0; r < 4; ++r) {
    int base = 0;
#pragma unroll
    for (int m = 0; m < 16; ++m) {
      unsigned ov = ordf(v[r][m]);
      bool f = ov <= pp[r];
      unsigned long long bal = __ballot(f);
      int slot = base + (int)__popcll(bal & mlt);
      if (f && slot < 64)
        sCmp[(w*4 + r)*64 + slot] =
            ((unsigned long long)ov << 32) |
            (unsigned)((m >> 1)*128 + lane*2 + (m & 1));
      base += (int)__popcll(bal);
    }
    total[r] = base;
  }

  unsigned cu2[4]; int col2[4];
#pragma unroll
  for (int r = 0; r < 4; ++r) {
    unsigned long long kp = (lane < total[r]) ? sCmp[(w*4 + r)*64 + lane] : ~0ull;
    cu2[r] = (unsigned)(kp >> 32);
    col2[r] = (int)(unsigned)(kp & 0xFFFFFFFFull);
  }

  if (MODE == 2) {
    // sCmp consumed; stage next-layer W fragments (32 KB) into sBuf[0..32768)
    __syncthreads();
#pragma unroll
    for (int i = 0; i < 2; ++i) {
      int I = w*2 + i;
      gl_lds16(WfN + (size_t)I*1024 + lane*16, (void*)(sBuf + I*1024));
    }
  }

  // phase 5: exact value bisection on candidates (full 32 bits — required)
  unsigned p2[4] = {0u, 0u, 0u, 0u};
#pragma unroll
  for (int bb = 31; bb >= 0; --bb) {
#pragma unroll
    for (int r = 0; r < 4; ++r) {
      unsigned q = p2[r] | (1u << bb);
      if ((int)__popcll(__ballot(cu2[r] < q)) < KK) p2[r] = q;
    }
  }
  int need[4]; bool tie[4]; int cntT[4];
#pragma unroll
  for (int r = 0; r < 4; ++r) {
    need[r] = KK - (int)__popcll(__ballot(cu2[r] < p2[r]));
    tie[r] = (cu2[r] == p2[r]);
    cntT[r] = (int)__popcll(__ballot(tie[r]));
  }
  unsigned p3[4];
  bool allexact = cntT[0] == need[0] && cntT[1] == need[1] &&
                  cntT[2] == need[2] && cntT[3] == need[3];
  if (allexact) {
#pragma unroll
    for (int r = 0; r < 4; ++r) p3[r] = 0xFFFFFFFFu;
  } else {
#pragma unroll
    for (int r = 0; r < 4; ++r) p3[r] = 0u;
#pragma unroll
    for (int bb = 9; bb >= 0; --bb) {
#pragma unroll
      for (int r = 0; r < 4; ++r) {
        unsigned q = p3[r] | (1u << bb);
        if ((int)__popcll(__ballot(tie[r] && ((unsigned)col2[r] < q))) < need[r]) p3[r] = q;
      }
    }
  }

  bool allfast = total[0] <= 64 && total[1] <= 64 && total[2] <= 64 && total[3] <= 64;
  if (allfast) {
#pragma unroll
    for (int r = 0; r < 4; ++r) {
      bool in24 = (cu2[r] < p2[r]) || (tie[r] && ((unsigned)col2[r] <= p3[r]));
      unsigned long long ball = __ballot(in24);
      int pos = (int)__popcll(ball & mlt);
      if (in24) nIdx[(w*4 + r)*KK + pos] = col2[r];
    }
  } else {
    // cold exact path (r19 ownership: col = (m>>1)*128 + lane*2 + (m&1))
#pragma unroll
    for (int r = 0; r < 4; ++r) {
      unsigned selm = 0;
      for (int it = 0; it < KK; ++it) {
        float bv = FLTMAX; int bj = 0x7fffffff;
#pragma unroll
        for (int m = 0; m < 16; ++m) {
          float vv = ((selm >> m) & 1) ? FLTMAX : v[r][m];
          int col = (m >> 1)*128 + lane*2 + (m & 1);
          bool bsel = vv < bv; bv = bsel ? vv : bv; bj = bsel ? col : bj;
        }
#pragma unroll
        for (int s = 32; s; s >>= 1) {
          float ov = __shfl_xor(bv, s); int oj = __shfl_xor(bj, s);
          bool bsel = (ov < bv) || (ov == bv && oj < bj);
          bv = bsel ? ov : bv; bj = bsel ? oj : bj;
        }
        if (lane == ((bj & 127) >> 1)) selm |= 1u << (((bj >> 7) << 1) | (bj & 1));
        if (lane == 0) nIdx[(w*4 + r)*KK + it] = bj;
      }
    }
  }

  // ---- fused aggregate ----
  if (MODE == 0) {
#pragma unroll
    for (int r = 0; r < 4; ++r) {
      int row = rowBase + w*4 + r;
      float mx = -FLTMAX;
#pragma unroll
      for (int tt = 0; tt < KK; ++tt) {
        int j = nIdx[(w*4 + r)*KK + tt];
        mx = fmaxf(mx, V[((size_t)(gbase + j))*64 + lane]);
      }
      size_t off = (size_t)(gbase + row)*64 + lane;
      F[off] += elu1(U[off] + mx);
    }
  } else if (MODE == 1) {
    float* sOutF = (float*)sRowB;              // [64][68]
#pragma unroll
    for (int r = 0; r < 4; ++r) {
      int row = rowBase + w*4 + r;
      float mx = -FLTMAX;
#pragma unroll
      for (int tt = 0; tt < KK; ++tt) {
        int j = nIdx[(w*4 + r)*KK + tt];
        mx = fmaxf(mx, V[((size_t)(gbase + j))*64 + lane]);
      }
      size_t off = (size_t)(gbase + row)*64 + lane;
      sOutF[(w*4 + r)*68 + lane] = F[off] + elu1(U[off] + mx);
    }
    __syncthreads();

    float* sW1o = (float*)sBuf;
    float* sW2o = sW1o + 64*64;
    float* sW3o = sW2o + 64*32;
    float* sB1o = sW3o + 32*8;
    float* sB2o = sB1o + 64;
    float* sB3o = sB2o + 32;
    float* sO1  = sB3o + 8;
    for (int i = t; i < 64*64; i += 1024) sW1o[i] = Wo1[i];
    for (int i = t; i < 64*32; i += 1024) sW2o[i] = Wo2[i];
    if (t < 256) sW3o[t] = Wo3[t];
    if (t < 64) sB1o[t] = bo1[t];
    if (t < 32) sB2o[t] = bo2[t];
    if (t < 8)  sB3o[t] = bo3[t];
    __syncthreads();

    int ln = t >> 3, qd = t & 7;
    if (t < 512) {
      float a1[8];
#pragma unroll
      for (int dd = 0; dd < 8; ++dd) a1[dd] = sB1o[qd*8 + dd];
#pragma unroll 4
      for (int k = 0; k < 64; ++k) {
        float fk = sOutF[ln*68 + k];
#pragma unroll
        for (int dd = 0; dd < 8; ++dd) a1[dd] += fk*sW1o[k*64 + qd*8 + dd];
      }
#pragma unroll
      for (int dd = 0; dd < 8; ++dd) sO1[ln*65 + qd*8 + dd] = elu1(a1[dd]);
    }
    __syncthreads();

    float* sO2 = (float*)sRowB;
    if (t < 512) {
      float a2[4];
#pragma unroll
      for (int dd = 0; dd < 4; ++dd) a2[dd] = sB2o[qd*4 + dd];
#pragma unroll 4
      for (int k = 0; k < 64; ++k) {
        float ok = sO1[ln*65 + k];
#pragma unroll
        for (int dd = 0; dd < 4; ++dd) a2[dd] += ok*sW2o[k*32 + qd*4 + dd];
      }
#pragma unroll
      for (int dd = 0; dd < 4; ++dd) sO2[ln*34 + qd*4 + dd] = elu1(a2[dd]);
    }
    __syncthreads();

    if (t < 512) {
      int nodeG = gbase + rowBase + ln;
      float a3 = sB3o[qd];
#pragma unroll
      for (int k = 0; k < 32; ++k) a3 += sO2[ln*34 + k]*sW3o[k*8 + qd];
      out[(size_t)nodeG*8 + qd] = a3;
      if (qd == 0 && out_size >= NN*9) out[(size_t)NN*8 + nodeG] = (float)batch[nodeG];
    }
  } else {
    // MODE 2: aggregate -> F global + LDS, then fused next-layer k_uv tail
    float* sOutF = (float*)sRowB;              // [64][68]
#pragma unroll
    for (int r = 0; r < 4; ++r) {
      int row = rowBase + w*4 + r;
      float mx = -FLTMAX;
#pragma unroll
      for (int tt = 0; tt < KK; ++tt) {
        int j = nIdx[(w*4 + r)*KK + tt];
        mx = fmaxf(mx, V[((size_t)(gbase + j))*64 + lane]);
      }
      size_t off = (size_t)(gbase + row)*64 + lane;
      float nf = F[off] + elu1(U[off] + mx);
      F[off] = nf;
      sOutF[(w*4 + r)*68 + lane] = nf;
    }
    asm volatile("s_waitcnt vmcnt(0)" ::: "memory");   // WfN staging done
    __builtin_amdgcn_sched_barrier(0);
    __syncthreads();

    unsigned char* sConvT = sBuf + 32768;
    if (t < 256) {
      int ln = t >> 2, q2 = t & 3;
      int ks = q2 >> 1, oh = (q2 & 1) * 2;
      const float* src = sOutF + ln*68 + ks*32 + oh*8;
      unsigned hu[8], lu[8];
      float sq = 0.f;
#pragma unroll
      for (int q = 0; q < 4; ++q) {
        float4 f = *reinterpret_cast<const float4*>(src + q*4);
        sq += f.x*f.x + f.y*f.y + f.z*f.z + f.w*f.w;
        unsigned short h0 = f2bf(f.x), h1 = f2bf(f.y), h2 = f2bf(f.z), h3 = f2bf(f.w);
        unsigned short l0 = f2bf(f.x - bf2f(h0)), l1 = f2bf(f.y - bf2f(h1));
        unsigned short l2 = f2bf(f.z - bf2f(h2)), l3 = f2bf(f.w - bf2f(h3));
        hu[q*2]   = (unsigned)h0 | ((unsigned)h1 << 16);
        hu[q*2+1] = (unsigned)h2 | ((unsigned)h3 << 16);
        lu[q*2]   = (unsigned)l0 | ((unsigned)l1 << 16);
        lu[q*2+1] = (unsigned)l2 | ((unsigned)l3 << 16);
      }
      sq += __shfl_xor(sq, 1);
      sq += __shfl_xor(sq, 2);
      if (q2 == 0) SQn[gbase + rowBase + ln] = sq;
      unsigned char* gdst = XBn + (((size_t)g*2 + ks)*1024 + rowBase + ln)*128 + oh*16;
#pragma unroll
      for (int o = 0; o < 2; ++o) {
        int4 hp = make_int4(hu[o*4], hu[o*4+1], hu[o*4+2], hu[o*4+3]);
        int4 lp = make_int4(lu[o*4], lu[o*4+1], lu[o*4+2], lu[o*4+3]);
        *reinterpret_cast<int4*>(sConvT + conv_off(ln, ks*8 + oh + o))     = hp;
        *reinterpret_cast<int4*>(sConvT + conv_off(ln, ks*8 + 4 + oh + o)) = lp;
        *reinterpret_cast<int4*>(gdst + o*16)      = hp;
        *reinterpret_cast<int4*>(gdst + 64 + o*16) = lp;
      }
    }
    __syncthreads();

    f32x4 acc2[2];
    acc2[0] = f32x4{0.f, 0.f, 0.f, 0.f};
    acc2[1] = f32x4{0.f, 0.f, 0.f, 0.f};
    int nodeT = (w & 3)*16 + a15;
    int ntp = w >> 2;
#pragma unroll
    for (int ks2 = 0; ks2 < 2; ++ks2) {
      short8 ah2 = *reinterpret_cast<const short8*>(sConvT + conv_off(nodeT, ks2*8 + g4));
      short8 al2 = *reinterpret_cast<const short8*>(sConvT + conv_off(nodeT, ks2*8 + 4 + g4));
#pragma unroll
      for (int q = 0; q < 2; ++q) {
        int nt = ntp + q*4;
        int fb = ((ks2*4 + g4)*8 + nt)*2;
        short8 bh = *reinterpret_cast<const short8*>(sBuf + fb*256 + a15*16);
        short8 bl = *reinterpret_cast<const short8*>(sBuf + (fb+1)*256 + a15*16);
        acc2[q] = __builtin_amdgcn_mfma_f32_16x16x32_bf16(ah2, bh, acc2[q], 0, 0, 0);
        acc2[q] = __builtin_amdgcn_mfma_f32_16x16x32_bf16(ah2, bl, acc2[q], 0, 0, 0);
        acc2[q] = __builtin_amdgcn_mfma_f32_16x16x32_bf16(al2, bh, acc2[q], 0, 0, 0);
        acc2[q] = __builtin_amdgcn_mfma_f32_16x16x32_bf16(al2, bl, acc2[q], 0, 0, 0);
      }
    }
    float bcv = bcN[ntp*16 + a15];
#pragma unroll
    for (int i = 0; i < 4; ++i) {
      size_t row = (size_t)gbase + rowBase + (w & 3)*16 + g4*4 + i;
      float p = acc2[0][i], q = acc2[1][i];
      Un[row*64 + ntp*16 + a15] = p - q + bcv;
      Vn[row*64 + ntp*16 + a15] = q;
    }
  }
}

extern "C" void kernel_launch(void* const* d_in, const int* in_sizes, int n_in,
                              void* d_out, int out_size, void* d_ws, size_t ws_size,
                              hipStream_t stream) {
  const float* x     = (const float*)d_in[0];
  const int*   batch = (const int*)d_in[1];
  const float* W1 = (const float*)d_in[2];
  const float* b1 = (const float*)d_in[3];
  const float* W2 = (const float*)d_in[4];
  const float* b2 = (const float*)d_in[5];
  const float* Wc[3] = {(const float*)d_in[6], (const float*)d_in[8], (const float*)d_in[10]};
  const float* bc[3] = {(const float*)d_in[7], (const float*)d_in[9], (const float*)d_in[11]};
  const float* Wo1 = (const float*)d_in[12];
  const float* bo1 = (const float*)d_in[13];
  const float* Wo2 = (const float*)d_in[14];
  const float* bo2 = (const float*)d_in[15];
  const float* Wo3 = (const float*)d_in[16];
  const float* bo3 = (const float*)d_in[17];

  float* outF = (float*)d_out;
  const size_t NEED = (size_t)(5*NN*64 + 2*NN)*4 + (size_t)2*NN*256 + 98304;

  if (ws_size >= NEED) {
    float* ws = (float*)d_ws;
    float* F0  = ws;
    float* U0  = F0 + (size_t)NN*64;
    float* V0  = U0 + (size_t)NN*64;
    float* U1  = V0 + (size_t)NN*64;
    float* V1  = U1 + (size_t)NN*64;
    float* SQ0 = V1 + (size_t)NN*64;
    float* SQ1 = SQ0 + NN;
    unsigned char* XB0 = (unsigned char*)(SQ1 + NN);
    unsigned char* XB1 = XB0 + (size_t)NN*256;
    unsigned char* WfG = XB1 + (size_t)NN*256;

    k_mlp_in<<<NN/128 + 3, 256, 0, stream>>>(x, W1, b1, W2, b2, F0,
                                             Wc[0], Wc[1], Wc[2], WfG);
    k_uv<<<NN/64, 256, 0, stream>>>(F0, WfG, bc[0], U0, V0, SQ0, XB0);
    k_knn<2><<<BG*(NPG/64), 1024, 0, stream>>>(XB0, SQ0, U0, V0, F0,
        Wo1, bo1, Wo2, bo2, Wo3, bo3, batch, outF, out_size,
        WfG + 32768, bc[1], U1, V1, SQ1, XB1);
    k_knn<2><<<BG*(NPG/64), 1024, 0, stream>>>(XB1, SQ1, U1, V1, F0,
        Wo1, bo1, Wo2, bo2, Wo3, bo3, batch, outF, out_size,
        WfG + 65536, bc[2], U0, V0, SQ0, XB0);
    k_knn<1><<<BG*(NPG/64), 1024, 0, stream>>>(XB0, SQ0, U0, V0, F0,
        Wo1, bo1, Wo2, bo2, Wo3, bo3, batch, outF, out_size,
        (const unsigned char*)0, (const float*)0,
        (float*)0, (float*)0, (float*)0, (unsigned char*)0);
  } else {
    float* ws = (float*)d_ws;
    float* F0 = ws;
    float* U  = ws + (size_t)NN*64;
    float* V  = ws + (size_t)2*NN*64;
    float* SQ = ws + (size_t)3*NN*64;
    unsigned char* XB = (unsigned char*)(SQ + NN);
    unsigned char* WfG = XB + (size_t)NN*256;

    k_mlp_in<<<NN/128 + 3, 256, 0, stream>>>(x, W1, b1, W2, b2, F0,
                                             Wc[0], Wc[1], Wc[2], WfG);
    for (int l = 0; l < 3; ++l) {
      k_uv<<<NN/64, 256, 0, stream>>>(F0, WfG + (size_t)l*32768, bc[l], U, V, SQ, XB);
      if (l < 2)
        k_knn<0><<<BG*(NPG/64), 1024, 0, stream>>>(XB, SQ, U, V, F0,
            Wo1, bo1, Wo2, bo2, Wo3, bo3, batch, outF, out_size,
            (const unsigned char*)0, (const float*)0,
            (float*)0, (float*)0, (float*)0, (unsigned char*)0);
      else
        k_knn<1><<<BG*(NPG/64), 1024, 0, stream>>>(XB, SQ, U, V, F0,
            Wo1, bo1, Wo2, bo2, Wo3, bo3, batch, outF, out_size,
            (const unsigned char*)0, (const float*)0,
            (float*)0, (float*)0, (float*)0, (unsigned char*)0);
    }
  }
}